// Round 1
// baseline (6330.133 us; speedup 1.0000x reference)
//
#include <hip/hip_runtime.h>
#include <hip/hip_bf16.h>

namespace {
constexpr int Bn = 128;
constexpr int Cn = 2048;
constexpr int Nn = 196;   // 14*14 spatial
constexpr int Sn = 312;
constexpr int Ln = 300;
constexpr int Mn = 1024;

constexpr size_t SZ_QUERY = (size_t)Sn * Mn;       // 319488
constexpr size_t SZ_POOL  = (size_t)Bn * Cn;       // 262144
constexpr size_t SZ_KV    = (size_t)Bn * Nn * Mn;  // 25690112
constexpr size_t SZ_ATTN  = (size_t)Bn * Sn * Nn;  // 7827456
constexpr size_t SZ_ATT   = (size_t)Bn * Sn * Mn;  // 40894464

constexpr size_t OFF_QUERY = 0;
constexpr size_t OFF_POOL  = OFF_QUERY + SZ_QUERY;
constexpr size_t OFF_KEY   = OFF_POOL + SZ_POOL;
constexpr size_t OFF_VAL   = OFF_KEY + SZ_KV;
constexpr size_t OFF_ATTN  = OFF_VAL + SZ_KV;
constexpr size_t OFF_ATT   = OFF_ATTN + SZ_ATTN;
// total ws floats = OFF_ATT + SZ_ATT = 100,683,776  (~403 MB)
}

// ---------------- query = w2v @ Wq + bq : [Sn, Mn] ----------------
__global__ __launch_bounds__(256) void k_query(
        const float* __restrict__ w2v, const float* __restrict__ Wq,
        const float* __restrict__ bq, float* __restrict__ qout) {
    __shared__ float a[Ln];
    const int s = blockIdx.x;
    const int m = blockIdx.y * 256 + threadIdx.x;
    for (int i = threadIdx.x; i < Ln; i += 256) a[i] = w2v[(size_t)s * Ln + i];
    __syncthreads();
    float acc = bq[m];
    #pragma unroll 4
    for (int k = 0; k < Ln; ++k) acc = fmaf(a[k], Wq[(size_t)k * Mn + m], acc);
    qout[(size_t)s * Mn + m] = acc;
}

// ---------------- feat_pool[b,c] = mean_n feat[b,c,n] ----------------
__global__ __launch_bounds__(256) void k_pool(
        const float* __restrict__ feat, float* __restrict__ pool) {
    const int row  = blockIdx.x * 4 + (threadIdx.x >> 6);  // [0, Bn*Cn)
    const int lane = threadIdx.x & 63;
    const float* p = feat + (size_t)row * Nn;
    float sum = p[lane] + p[lane + 64] + p[lane + 128];
    if (lane < 4) sum += p[lane + 192];
    #pragma unroll
    for (int m = 32; m; m >>= 1) sum += __shfl_xor(sum, m);
    if (lane == 0) pool[row] = sum * (1.0f / Nn);
}

// -------- key/value[bn, m] = sum_c feat[b,c,n]*W[c,m] + bias --------
// rows = Bn*Nn = 25088 (tile 128), cols = Mn (tile 128), BK = 8
__global__ __launch_bounds__(256) void k_kv(
        const float* __restrict__ feat,
        const float* __restrict__ Wk, const float* __restrict__ bk,
        const float* __restrict__ Wv, const float* __restrict__ bv,
        float* __restrict__ key, float* __restrict__ value) {
    constexpr int LDA = 132;
    __shared__ __align__(16) float As[8][LDA];
    __shared__ __align__(16) float Ks[8][LDA];
    __shared__ __align__(16) float Vs[8][LDA];
    const int t  = threadIdx.x;
    const int c0 = blockIdx.x * 128;   // x fastest: consecutive blocks share feat tile
    const int r0 = blockIdx.y * 128;
    const int tr = t >> 4;             // rows tr*8 .. tr*8+7
    const int tc = t & 15;             // cols tc*8 .. tc*8+7

    // A-load mapping (scalar, coalesced along rows)
    const int rl   = t & 127;
    const int klA0 = t >> 7;           // 0 or 1
    const int r    = r0 + rl;
    const int bb   = r / Nn;
    const int nn   = r - bb * Nn;
    const size_t abase = (size_t)bb * Cn * Nn + nn;

    // W-load mapping (one float4 per array)
    const int klW = t >> 5;            // 0..7
    const int cW  = (t & 31) * 4;

    float acck[8][8], accv[8][8];
    #pragma unroll
    for (int i = 0; i < 8; ++i)
        #pragma unroll
        for (int j = 0; j < 8; ++j) { acck[i][j] = 0.f; accv[i][j] = 0.f; }

    for (int k0 = 0; k0 < Cn; k0 += 8) {
        #pragma unroll
        for (int p = 0; p < 4; ++p) {
            const int kl = klA0 + 2 * p;
            As[kl][rl] = feat[abase + (size_t)(k0 + kl) * Nn];
        }
        *(float4*)&Ks[klW][cW] = *(const float4*)&Wk[(size_t)(k0 + klW) * Mn + c0 + cW];
        *(float4*)&Vs[klW][cW] = *(const float4*)&Wv[(size_t)(k0 + klW) * Mn + c0 + cW];
        __syncthreads();
        #pragma unroll
        for (int kk = 0; kk < 8; ++kk) {
            float a[8], wk[8], wv[8];
            *(float4*)&a[0]  = *(float4*)&As[kk][tr * 8];
            *(float4*)&a[4]  = *(float4*)&As[kk][tr * 8 + 4];
            *(float4*)&wk[0] = *(float4*)&Ks[kk][tc * 8];
            *(float4*)&wk[4] = *(float4*)&Ks[kk][tc * 8 + 4];
            *(float4*)&wv[0] = *(float4*)&Vs[kk][tc * 8];
            *(float4*)&wv[4] = *(float4*)&Vs[kk][tc * 8 + 4];
            #pragma unroll
            for (int i = 0; i < 8; ++i)
                #pragma unroll
                for (int j = 0; j < 8; ++j) {
                    acck[i][j] = fmaf(a[i], wk[j], acck[i][j]);
                    accv[i][j] = fmaf(a[i], wv[j], accv[i][j]);
                }
        }
        __syncthreads();
    }

    float bka[8], bva[8];
    *(float4*)&bka[0] = *(const float4*)&bk[c0 + tc * 8];
    *(float4*)&bka[4] = *(const float4*)&bk[c0 + tc * 8 + 4];
    *(float4*)&bva[0] = *(const float4*)&bv[c0 + tc * 8];
    *(float4*)&bva[4] = *(const float4*)&bv[c0 + tc * 8 + 4];
    #pragma unroll
    for (int i = 0; i < 8; ++i) {
        const size_t row = (size_t)(r0 + tr * 8 + i);
        float ok[8], ov[8];
        #pragma unroll
        for (int j = 0; j < 8; ++j) { ok[j] = acck[i][j] + bka[j]; ov[j] = accv[i][j] + bva[j]; }
        *(float4*)&key[row * Mn + c0 + tc * 8]       = *(float4*)&ok[0];
        *(float4*)&key[row * Mn + c0 + tc * 8 + 4]   = *(float4*)&ok[4];
        *(float4*)&value[row * Mn + c0 + tc * 8]     = *(float4*)&ov[0];
        *(float4*)&value[row * Mn + c0 + tc * 8 + 4] = *(float4*)&ov[4];
    }
}

// ------- attn[b,s,n] = softmax_n( sum_m query[s,m]*key[b,n,m] ) -------
// block: 64 s-rows x all 196 n; K-chunks of 32
__global__ __launch_bounds__(256) void k_scores(
        const float* __restrict__ query, const float* __restrict__ key,
        float* __restrict__ attn) {
    __shared__ __align__(16) float Qs[64][36];
    __shared__ __align__(16) float Ksh[196][36];
    const int b  = blockIdx.y;
    const int s0 = blockIdx.x * 64;
    const int t  = threadIdx.x;
    const int sl = t >> 4;   // 0..15 -> s rows sl, sl+16, sl+32, sl+48
    const int g  = t & 15;   // n = g + 16*j, j<13 (n<196)

    float acc[4][13];
    #pragma unroll
    for (int a = 0; a < 4; ++a)
        #pragma unroll
        for (int j = 0; j < 13; ++j) acc[a][j] = 0.f;

    const float* keyb = key + (size_t)b * Nn * Mn;

    for (int k0 = 0; k0 < Mn; k0 += 32) {
        #pragma unroll
        for (int p = 0; p < 2; ++p) {
            const int idx = t + 256 * p;
            const int sq = idx >> 3;
            const int kq = (idx & 7) * 4;
            const int s = s0 + sq;
            float4 q4 = (s < Sn) ? *(const float4*)&query[(size_t)s * Mn + k0 + kq]
                                 : make_float4(0.f, 0.f, 0.f, 0.f);
            *(float4*)&Qs[sq][kq] = q4;
        }
        for (int idx = t; idx < 1568; idx += 256) {
            const int n  = idx >> 3;
            const int kq = (idx & 7) * 4;
            *(float4*)&Ksh[n][kq] = *(const float4*)&keyb[(size_t)n * Mn + k0 + kq];
        }
        __syncthreads();
        #pragma unroll
        for (int kk = 0; kk < 32; kk += 4) {
            float4 q0 = *(float4*)&Qs[sl][kk];
            float4 q1 = *(float4*)&Qs[sl + 16][kk];
            float4 q2 = *(float4*)&Qs[sl + 32][kk];
            float4 q3 = *(float4*)&Qs[sl + 48][kk];
            #pragma unroll
            for (int j = 0; j < 13; ++j) {
                if (j < 12 || g < 4) {
                    float4 k4 = *(float4*)&Ksh[g + 16 * j][kk];
                    acc[0][j] = fmaf(q0.x,k4.x,fmaf(q0.y,k4.y,fmaf(q0.z,k4.z,fmaf(q0.w,k4.w,acc[0][j]))));
                    acc[1][j] = fmaf(q1.x,k4.x,fmaf(q1.y,k4.y,fmaf(q1.z,k4.z,fmaf(q1.w,k4.w,acc[1][j]))));
                    acc[2][j] = fmaf(q2.x,k4.x,fmaf(q2.y,k4.y,fmaf(q2.z,k4.z,fmaf(q2.w,k4.w,acc[2][j]))));
                    acc[3][j] = fmaf(q3.x,k4.x,fmaf(q3.y,k4.y,fmaf(q3.z,k4.z,fmaf(q3.w,k4.w,acc[3][j]))));
                }
            }
        }
        __syncthreads();
    }

    // softmax over n (distributed across the 16 g-lanes of each s group)
    #pragma unroll
    for (int a = 0; a < 4; ++a) {
        const int s = s0 + sl + a * 16;
        float mx = -1e30f;
        #pragma unroll
        for (int j = 0; j < 13; ++j)
            if (j < 12 || g < 4) mx = fmaxf(mx, acc[a][j]);
        #pragma unroll
        for (int mm = 1; mm < 16; mm <<= 1) mx = fmaxf(mx, __shfl_xor(mx, mm));
        float sum = 0.f;
        float pr[13];
        #pragma unroll
        for (int j = 0; j < 13; ++j) {
            pr[j] = (j < 12 || g < 4) ? __expf(acc[a][j] - mx) : 0.f;
            sum += pr[j];
        }
        #pragma unroll
        for (int mm = 1; mm < 16; mm <<= 1) sum += __shfl_xor(sum, mm);
        const float inv = 1.0f / sum;
        if (s < Sn) {
            float* arow = attn + ((size_t)b * Sn + s) * Nn;
            #pragma unroll
            for (int j = 0; j < 13; ++j)
                if (j < 12 || g < 4) arow[g + 16 * j] = pr[j] * inv;
        }
    }
}

// -------- attented[b,s,m] = sum_n attn[b,s,n]*value[b,n,m] --------
// tile 64s x 64m, BK = 28 (196 = 7*28)
__global__ __launch_bounds__(256) void k_pv(
        const float* __restrict__ attn, const float* __restrict__ value,
        float* __restrict__ att) {
    __shared__ __align__(16) float As[28][68];
    __shared__ __align__(16) float Bs[28][68];
    const int t  = threadIdx.x;
    const int m0 = blockIdx.x * 64;
    const int s0 = blockIdx.y * 64;
    const int b  = blockIdx.z;
    const int tr = t >> 4, tc = t & 15;
    const float* attb = attn + (size_t)b * Sn * Nn;
    const float* valb = value + (size_t)b * Nn * Mn;
    float acc[4][4];
    #pragma unroll
    for (int i = 0; i < 4; ++i)
        #pragma unroll
        for (int j = 0; j < 4; ++j) acc[i][j] = 0.f;

    for (int k0 = 0; k0 < Nn; k0 += 28) {
        for (int idx = t; idx < 448; idx += 256) {   // A: 64 rows x 7 float4, transposed
            const int srow = idx / 7;
            const int fq = idx - srow * 7;
            const int s = s0 + srow;
            float4 a4 = (s < Sn) ? *(const float4*)&attb[(size_t)s * Nn + k0 + fq * 4]
                                 : make_float4(0.f, 0.f, 0.f, 0.f);
            As[fq * 4 + 0][srow] = a4.x;
            As[fq * 4 + 1][srow] = a4.y;
            As[fq * 4 + 2][srow] = a4.z;
            As[fq * 4 + 3][srow] = a4.w;
        }
        for (int idx = t; idx < 448; idx += 256) {   // B: 28 k x 64 m
            const int kl = idx >> 4;
            const int m4 = (idx & 15) * 4;
            *(float4*)&Bs[kl][m4] = *(const float4*)&valb[(size_t)(k0 + kl) * Mn + m0 + m4];
        }
        __syncthreads();
        #pragma unroll
        for (int kk = 0; kk < 28; ++kk) {
            float4 a4 = *(float4*)&As[kk][tr * 4];
            float4 b4 = *(float4*)&Bs[kk][tc * 4];
            float aa[4] = {a4.x, a4.y, a4.z, a4.w};
            float wb[4] = {b4.x, b4.y, b4.z, b4.w};
            #pragma unroll
            for (int i = 0; i < 4; ++i)
                #pragma unroll
                for (int j = 0; j < 4; ++j)
                    acc[i][j] = fmaf(aa[i], wb[j], acc[i][j]);
        }
        __syncthreads();
    }
    #pragma unroll
    for (int i = 0; i < 4; ++i) {
        const int s = s0 + tr * 4 + i;
        if (s < Sn) {
            float4 o = {acc[i][0], acc[i][1], acc[i][2], acc[i][3]};
            *(float4*)&att[((size_t)b * Sn + s) * Mn + m0 + tc * 4] = o;
        }
    }
}

// ---- v2s[b,s] += sum_c (pool[b,c] + bo[c] + att[bs,:]@Wo[:,c]) * V[s,c] ----
// rows = Bn*Sn = 39936 (tile 256), cols = Cn (tile 128), BK = 8; atomic per row
__global__ __launch_bounds__(256) void k_out(
        const float* __restrict__ att, const float* __restrict__ Wo,
        const float* __restrict__ bo, const float* __restrict__ pool,
        const float* __restrict__ Vf, float* __restrict__ out) {
    constexpr int LDA = 260;
    constexpr int LDW = 132;
    __shared__ __align__(16) float As[8][LDA];
    __shared__ __align__(16) float Ws[8][LDW];
    const int t  = threadIdx.x;
    const int c0 = blockIdx.x * 128;   // x fastest: consecutive blocks share A row-tile
    const int r0 = blockIdx.y * 256;
    const int tr = t >> 4;             // rows tr*16 .. +15
    const int tc = t & 15;             // cols tc*8 .. +7
    const int klW = t >> 5;
    const int cW  = (t & 31) * 4;

    float acc[16][8];
    #pragma unroll
    for (int i = 0; i < 16; ++i)
        #pragma unroll
        for (int j = 0; j < 8; ++j) acc[i][j] = 0.f;

    for (int k0 = 0; k0 < Mn; k0 += 8) {
        #pragma unroll
        for (int p = 0; p < 2; ++p) {   // A: 256 rows x 2 float4, transposed
            const int idx = t + 256 * p;
            const int rl = idx >> 1;
            const int f4 = idx & 1;
            float4 a4 = *(const float4*)&att[(size_t)(r0 + rl) * Mn + k0 + f4 * 4];
            As[f4 * 4 + 0][rl] = a4.x;
            As[f4 * 4 + 1][rl] = a4.y;
            As[f4 * 4 + 2][rl] = a4.z;
            As[f4 * 4 + 3][rl] = a4.w;
        }
        *(float4*)&Ws[klW][cW] = *(const float4*)&Wo[(size_t)(k0 + klW) * Cn + c0 + cW];
        __syncthreads();
        #pragma unroll
        for (int kk = 0; kk < 8; ++kk) {
            float a[16], w[8];
            *(float4*)&a[0]  = *(float4*)&As[kk][tr * 16];
            *(float4*)&a[4]  = *(float4*)&As[kk][tr * 16 + 4];
            *(float4*)&a[8]  = *(float4*)&As[kk][tr * 16 + 8];
            *(float4*)&a[12] = *(float4*)&As[kk][tr * 16 + 12];
            *(float4*)&w[0]  = *(float4*)&Ws[kk][tc * 8];
            *(float4*)&w[4]  = *(float4*)&Ws[kk][tc * 8 + 4];
            #pragma unroll
            for (int i = 0; i < 16; ++i)
                #pragma unroll
                for (int j = 0; j < 8; ++j)
                    acc[i][j] = fmaf(a[i], w[j], acc[i][j]);
        }
        __syncthreads();
    }

    // epilogue: final = pool + bo + acc; dot with V[s,:]; reduce c across tc-group
    #pragma unroll
    for (int i = 0; i < 16; ++i) {
        const int rr = r0 + tr * 16 + i;
        const int bb = rr / Sn;
        const int ss = rr - bb * Sn;
        float part = 0.f;
        #pragma unroll
        for (int j = 0; j < 8; ++j) {
            const int c = c0 + tc * 8 + j;
            const float fin = pool[(size_t)bb * Cn + c] + bo[c] + acc[i][j];
            part = fmaf(fin, Vf[(size_t)ss * Cn + c], part);
        }
        #pragma unroll
        for (int mm = 1; mm < 16; mm <<= 1) part += __shfl_xor(part, mm);
        if (tc == 0) atomicAdd(&out[rr], part);
    }
}

extern "C" void kernel_launch(void* const* d_in, const int* in_sizes, int n_in,
                              void* d_out, int out_size, void* d_ws, size_t ws_size,
                              hipStream_t stream) {
    (void)in_sizes; (void)n_in; (void)ws_size;
    const float* feat = (const float*)d_in[0];
    const float* w2v  = (const float*)d_in[1];
    const float* Wq   = (const float*)d_in[2];
    const float* bq   = (const float*)d_in[3];
    const float* Wk   = (const float*)d_in[4];
    const float* bk   = (const float*)d_in[5];
    const float* Wv   = (const float*)d_in[6];
    const float* bv   = (const float*)d_in[7];
    const float* Wo   = (const float*)d_in[8];
    const float* bo   = (const float*)d_in[9];
    const float* Vf   = (const float*)d_in[10];
    float* out = (float*)d_out;
    float* ws  = (float*)d_ws;

    float* q_buf = ws + OFF_QUERY;
    float* pool  = ws + OFF_POOL;
    float* key   = ws + OFF_KEY;
    float* value = ws + OFF_VAL;
    float* attn  = ws + OFF_ATTN;
    float* att   = ws + OFF_ATT;

    hipMemsetAsync(d_out, 0, (size_t)out_size * sizeof(float), stream);

    k_query <<<dim3(Sn, Mn / 256), 256, 0, stream>>>(w2v, Wq, bq, q_buf);
    k_pool  <<<dim3((Bn * Cn) / 4), 256, 0, stream>>>(feat, pool);
    k_kv    <<<dim3(Mn / 128, (Bn * Nn) / 128), 256, 0, stream>>>(feat, Wk, bk, Wv, bv, key, value);
    k_scores<<<dim3((Sn + 63) / 64, Bn), 256, 0, stream>>>(q_buf, key, attn);
    k_pv    <<<dim3(Mn / 64, (Sn + 63) / 64, Bn), 256, 0, stream>>>(attn, value, att);
    k_out   <<<dim3(Cn / 128, (Bn * Sn) / 256), 256, 0, stream>>>(att, Wo, bo, pool, Vf, out);
}

// Round 2
// 2391.805 us; speedup vs baseline: 2.6466x; 2.6466x over previous
//
#include <hip/hip_runtime.h>
#include <hip/hip_bf16.h>

namespace {
constexpr int Bn = 128;
constexpr int Cn = 2048;
constexpr int Nn = 196;   // 14*14 spatial
constexpr int Sn = 312;
constexpr int Ln = 300;
constexpr int Mn = 1024;

// workspace layout (units: f32 elements)
constexpr size_t OFF_Q    = 0;                      // 319488
constexpr size_t OFF_POOL = 319488;                 // 262144
constexpr size_t OFF_KEY  = 581632;                 // 25690112 f32
constexpr size_t OFF_VALB = 26271744;               // 25690112 bf16 = 12845056 f32
constexpr size_t OFF_FT   = 39116800;               // fT hi+lo: 2*51380224 bf16 = 51380224 f32
constexpr size_t OFF_ATTN = OFF_FT;                 // alias (fT dead after k_kv): 7827456 f32
constexpr size_t OFF_ATTB = OFF_FT + 7827456;       // att bf16: 40894464 bf16 = 20447232 f32
constexpr size_t OFF_WKH  = 90497024;               // each W: 2097152 bf16 = 1048576 f32
constexpr size_t OFF_WKL  = 91545600;
constexpr size_t OFF_WVH  = 92594176;
constexpr size_t OFF_WOH  = 93642752;
// total = 94691328 f32 = 378.8 MB  (round-1 used 402.7 MB successfully)
}

typedef __attribute__((ext_vector_type(8))) short bf16x8;
typedef __attribute__((ext_vector_type(4))) float f32x4;

__device__ __forceinline__ ushort f2bf(float x) {
    __hip_bfloat16 b = __float2bfloat16(x);
    return *reinterpret_cast<ushort*>(&b);
}
__device__ __forceinline__ float bf2f(ushort u) {
    __hip_bfloat16 b;
    *reinterpret_cast<ushort*>(&b) = u;
    return __bfloat162float(b);
}

__device__ __forceinline__ void gload16(void* lds, const void* g) {
    __builtin_amdgcn_global_load_lds(
        (const __attribute__((address_space(1))) void*)g,
        (__attribute__((address_space(3))) void*)lds, 16, 0, 0);
}

// stage a [128 rows x 32 k] bf16 tile; LDS linear row-major (64 B/row),
// XOR-swizzle (chunk ^= (row>>1)&3) applied on the SOURCE address so the
// swizzled ds_read_b128 frag fetches are conflict-free (2-way max).
__device__ __forceinline__ void stage_tile(ushort* lds, const ushort* src,
                                           size_t row0, int k0, int ld, int tid) {
    const int lane = tid & 63, wid = tid >> 6;
    #pragma unroll
    for (int is = 0; is < 2; ++is) {
        const int slot = wid * 64 + lane + is * 256;   // 512 slots of 16 B
        const int r = slot >> 2, q = slot & 3;
        const int qs = q ^ ((r >> 1) & 3);
        gload16(lds + (size_t)(wid * 64 + is * 256) * 8,
                src + (row0 + r) * (size_t)ld + k0 + qs * 8);
    }
}

// read one 16x32 A/B fragment (lane l: row = fr*16 + (l&15), k-chunk = l>>4)
__device__ __forceinline__ bf16x8 frag_ld(const ushort* tile, int fr, int lane) {
    const int rl = lane & 15;
    const int q  = (lane >> 4) ^ ((rl >> 1) & 3);
    return *(const bf16x8*)(tile + ((fr * 16 + rl) * 32 + q * 8));
}

// ---------------- query = w2v @ Wq + bq : [Sn, Mn] ----------------
__global__ __launch_bounds__(256) void k_query(
        const float* __restrict__ w2v, const float* __restrict__ Wq,
        const float* __restrict__ bq, float* __restrict__ qout) {
    __shared__ float a[Ln];
    const int s = blockIdx.x;
    const int m = blockIdx.y * 256 + threadIdx.x;
    for (int i = threadIdx.x; i < Ln; i += 256) a[i] = w2v[(size_t)s * Ln + i];
    __syncthreads();
    float acc = bq[m];
    #pragma unroll 4
    for (int k = 0; k < Ln; ++k) acc = fmaf(a[k], Wq[(size_t)k * Mn + m], acc);
    qout[(size_t)s * Mn + m] = acc;
}

// ---------------- feat_pool[b,c] = mean_n feat[b,c,n] ----------------
__global__ __launch_bounds__(256) void k_pool(
        const float* __restrict__ feat, float* __restrict__ pool) {
    const int row  = blockIdx.x * 4 + (threadIdx.x >> 6);
    const int lane = threadIdx.x & 63;
    const float* p = feat + (size_t)row * Nn;
    float sum = p[lane] + p[lane + 64] + p[lane + 128];
    if (lane < 4) sum += p[lane + 192];
    #pragma unroll
    for (int m = 32; m; m >>= 1) sum += __shfl_xor(sum, m);
    if (lane == 0) pool[row] = sum * (1.0f / Nn);
}

// ---- transpose feat[b][c][n] -> fT_hi/lo[(b*196+n)][c]  (bf16 hi+lo) ----
__global__ __launch_bounds__(256) void k_prep_feat(
        const float* __restrict__ feat, ushort* __restrict__ fhi,
        ushort* __restrict__ flo) {
    __shared__ float t[64][197];
    const int b = blockIdx.x, c0 = blockIdx.y * 64;
    for (int idx = threadIdx.x; idx < 64 * Nn; idx += 256) {
        const int r = idx / Nn, n = idx - r * Nn;
        t[r][n] = feat[((size_t)b * Cn + c0 + r) * Nn + n];
    }
    __syncthreads();
    for (int idx = threadIdx.x; idx < Nn * 64; idx += 256) {
        const int n = idx >> 6, c = idx & 63;
        const float v = t[c][n];
        const ushort h = f2bf(v);
        const size_t o = ((size_t)b * Nn + n) * Cn + c0 + c;
        fhi[o] = h;
        flo[o] = f2bf(v - bf2f(h));
    }
}

// ---- generic transpose+convert: in[R][Cc] f32 -> out_hi/lo[Cc][R] bf16 ----
__global__ __launch_bounds__(256) void k_transpose_cvt(
        const float* __restrict__ in, ushort* __restrict__ out_hi,
        ushort* __restrict__ out_lo, int R, int Cc) {
    __shared__ float t[64][65];
    const int co = blockIdx.x * 64, ro = blockIdx.y * 64;
    for (int idx = threadIdx.x; idx < 64 * 64; idx += 256) {
        const int r = idx >> 6, c = idx & 63;
        t[r][c] = in[(size_t)(ro + r) * Cc + co + c];
    }
    __syncthreads();
    for (int idx = threadIdx.x; idx < 64 * 64; idx += 256) {
        const int c = idx >> 6, r = idx & 63;
        const float v = t[r][c];
        const ushort h = f2bf(v);
        const size_t o = (size_t)(co + c) * R + ro + r;
        out_hi[o] = h;
        if (out_lo) out_lo[o] = f2bf(v - bf2f(h));
    }
}

// ---- key/value projection via MFMA: key split-bf16 (3 passes), value bf16 ----
// rows = Bn*Nn = 25088 (tile 128), cols = Mn (tile 128), BK = 32
__global__ __launch_bounds__(256, 2) void k_kv_mfma(
        const ushort* __restrict__ fhi, const ushort* __restrict__ flo,
        const ushort* __restrict__ wkh, const ushort* __restrict__ wkl,
        const ushort* __restrict__ wvh,
        const float* __restrict__ bk, const float* __restrict__ bv,
        float* __restrict__ key, ushort* __restrict__ valb) {
    __shared__ __align__(16) ushort sAh[128 * 32], sAl[128 * 32];
    __shared__ __align__(16) ushort sKh[128 * 32], sKl[128 * 32], sVh[128 * 32];
    const int tid = threadIdx.x, lane = tid & 63, wid = tid >> 6;
    const size_t r0 = (size_t)blockIdx.y * 128;
    const int m0 = blockIdx.x * 128;

    f32x4 acck[4][4], accv[4][4];
    #pragma unroll
    for (int i = 0; i < 4; ++i)
        #pragma unroll
        for (int j = 0; j < 4; ++j) { acck[i][j] = (f32x4)0.f; accv[i][j] = (f32x4)0.f; }

    const int fmb = (wid >> 1) * 4, fnb = (wid & 1) * 4;

    for (int k0 = 0; k0 < Cn; k0 += 32) {
        stage_tile(sAh, fhi, r0, k0, Cn, tid);
        stage_tile(sAl, flo, r0, k0, Cn, tid);
        stage_tile(sKh, wkh, m0, k0, Cn, tid);
        stage_tile(sKl, wkl, m0, k0, Cn, tid);
        stage_tile(sVh, wvh, m0, k0, Cn, tid);
        __syncthreads();
        bf16x8 ah[4], al[4];
        #pragma unroll
        for (int i = 0; i < 4; ++i) {
            ah[i] = frag_ld(sAh, fmb + i, lane);
            al[i] = frag_ld(sAl, fmb + i, lane);
        }
        #pragma unroll
        for (int j = 0; j < 4; ++j) {
            const bf16x8 bh = frag_ld(sKh, fnb + j, lane);
            const bf16x8 bl = frag_ld(sKl, fnb + j, lane);
            const bf16x8 bb = frag_ld(sVh, fnb + j, lane);
            #pragma unroll
            for (int i = 0; i < 4; ++i) {
                acck[i][j] = __builtin_amdgcn_mfma_f32_16x16x32_bf16(ah[i], bh, acck[i][j], 0, 0, 0);
                acck[i][j] = __builtin_amdgcn_mfma_f32_16x16x32_bf16(ah[i], bl, acck[i][j], 0, 0, 0);
                acck[i][j] = __builtin_amdgcn_mfma_f32_16x16x32_bf16(al[i], bh, acck[i][j], 0, 0, 0);
                accv[i][j] = __builtin_amdgcn_mfma_f32_16x16x32_bf16(ah[i], bb, accv[i][j], 0, 0, 0);
            }
        }
        __syncthreads();
    }

    const int rw = (wid >> 1) * 64;
    const int cw = m0 + (wid & 1) * 64;
    #pragma unroll
    for (int j = 0; j < 4; ++j) {
        const int col = cw + j * 16 + (lane & 15);
        const float bkc = bk[col], bvc = bv[col];
        #pragma unroll
        for (int i = 0; i < 4; ++i) {
            const size_t rbase = r0 + rw + i * 16 + (lane >> 4) * 4;
            #pragma unroll
            for (int rr = 0; rr < 4; ++rr) {
                key[(rbase + rr) * Mn + col] = acck[i][j][rr] + bkc;
                valb[(rbase + rr) * Mn + col] = f2bf(accv[i][j][rr] + bvc);
            }
        }
    }
}

// ------- attn[b,s,n] = softmax_n( sum_m query[s,m]*key[b,n,m] ) -------
__global__ __launch_bounds__(256) void k_scores(
        const float* __restrict__ query, const float* __restrict__ key,
        float* __restrict__ attn) {
    __shared__ __align__(16) float Qs[64][36];
    __shared__ __align__(16) float Ksh[196][36];
    const int b  = blockIdx.y;
    const int s0 = blockIdx.x * 64;
    const int t  = threadIdx.x;
    const int sl = t >> 4;
    const int g  = t & 15;

    float acc[4][13];
    #pragma unroll
    for (int a = 0; a < 4; ++a)
        #pragma unroll
        for (int j = 0; j < 13; ++j) acc[a][j] = 0.f;

    const float* keyb = key + (size_t)b * Nn * Mn;

    for (int k0 = 0; k0 < Mn; k0 += 32) {
        #pragma unroll
        for (int p = 0; p < 2; ++p) {
            const int idx = t + 256 * p;
            const int sq = idx >> 3;
            const int kq = (idx & 7) * 4;
            const int s = s0 + sq;
            float4 q4 = (s < Sn) ? *(const float4*)&query[(size_t)s * Mn + k0 + kq]
                                 : make_float4(0.f, 0.f, 0.f, 0.f);
            *(float4*)&Qs[sq][kq] = q4;
        }
        for (int idx = t; idx < 1568; idx += 256) {
            const int n  = idx >> 3;
            const int kq = (idx & 7) * 4;
            *(float4*)&Ksh[n][kq] = *(const float4*)&keyb[(size_t)n * Mn + k0 + kq];
        }
        __syncthreads();
        #pragma unroll
        for (int kk = 0; kk < 32; kk += 4) {
            float4 q0 = *(float4*)&Qs[sl][kk];
            float4 q1 = *(float4*)&Qs[sl + 16][kk];
            float4 q2 = *(float4*)&Qs[sl + 32][kk];
            float4 q3 = *(float4*)&Qs[sl + 48][kk];
            #pragma unroll
            for (int j = 0; j < 13; ++j) {
                if (j < 12 || g < 4) {
                    float4 k4 = *(float4*)&Ksh[g + 16 * j][kk];
                    acc[0][j] = fmaf(q0.x,k4.x,fmaf(q0.y,k4.y,fmaf(q0.z,k4.z,fmaf(q0.w,k4.w,acc[0][j]))));
                    acc[1][j] = fmaf(q1.x,k4.x,fmaf(q1.y,k4.y,fmaf(q1.z,k4.z,fmaf(q1.w,k4.w,acc[1][j]))));
                    acc[2][j] = fmaf(q2.x,k4.x,fmaf(q2.y,k4.y,fmaf(q2.z,k4.z,fmaf(q2.w,k4.w,acc[2][j]))));
                    acc[3][j] = fmaf(q3.x,k4.x,fmaf(q3.y,k4.y,fmaf(q3.z,k4.z,fmaf(q3.w,k4.w,acc[3][j]))));
                }
            }
        }
        __syncthreads();
    }

    #pragma unroll
    for (int a = 0; a < 4; ++a) {
        const int s = s0 + sl + a * 16;
        float mx = -1e30f;
        #pragma unroll
        for (int j = 0; j < 13; ++j)
            if (j < 12 || g < 4) mx = fmaxf(mx, acc[a][j]);
        #pragma unroll
        for (int mm = 1; mm < 16; mm <<= 1) mx = fmaxf(mx, __shfl_xor(mx, mm));
        float sum = 0.f;
        float pr[13];
        #pragma unroll
        for (int j = 0; j < 13; ++j) {
            pr[j] = (j < 12 || g < 4) ? __expf(acc[a][j] - mx) : 0.f;
            sum += pr[j];
        }
        #pragma unroll
        for (int mm = 1; mm < 16; mm <<= 1) sum += __shfl_xor(sum, mm);
        const float inv = 1.0f / sum;
        if (s < Sn) {
            float* arow = attn + ((size_t)b * Sn + s) * Nn;
            #pragma unroll
            for (int j = 0; j < 13; ++j)
                if (j < 12 || g < 4) arow[g + 16 * j] = pr[j] * inv;
        }
    }
}

// -------- att_bf16[b,s,m] = sum_n attn[b,s,n]*value[b,n,m] --------
__global__ __launch_bounds__(256) void k_pv(
        const float* __restrict__ attn, const ushort* __restrict__ valb,
        ushort* __restrict__ att) {
    __shared__ __align__(16) float As[28][68];
    __shared__ __align__(16) float Bs[28][68];
    const int t  = threadIdx.x;
    const int m0 = blockIdx.x * 64;
    const int s0 = blockIdx.y * 64;
    const int b  = blockIdx.z;
    const int tr = t >> 4, tc = t & 15;
    const float* attb = attn + (size_t)b * Sn * Nn;
    const ushort* vb = valb + (size_t)b * Nn * Mn;
    float acc[4][4];
    #pragma unroll
    for (int i = 0; i < 4; ++i)
        #pragma unroll
        for (int j = 0; j < 4; ++j) acc[i][j] = 0.f;

    for (int k0 = 0; k0 < Nn; k0 += 28) {
        for (int idx = t; idx < 448; idx += 256) {
            const int srow = idx / 7;
            const int fq = idx - srow * 7;
            const int s = s0 + srow;
            float4 a4 = (s < Sn) ? *(const float4*)&attb[(size_t)s * Nn + k0 + fq * 4]
                                 : make_float4(0.f, 0.f, 0.f, 0.f);
            As[fq * 4 + 0][srow] = a4.x;
            As[fq * 4 + 1][srow] = a4.y;
            As[fq * 4 + 2][srow] = a4.z;
            As[fq * 4 + 3][srow] = a4.w;
        }
        for (int idx = t; idx < 448; idx += 256) {
            const int kl = idx >> 4;
            const int m4 = (idx & 15) * 4;
            ushort4 u = *(const ushort4*)&vb[(size_t)(k0 + kl) * Mn + m0 + m4];
            Bs[kl][m4 + 0] = bf2f(u.x);
            Bs[kl][m4 + 1] = bf2f(u.y);
            Bs[kl][m4 + 2] = bf2f(u.z);
            Bs[kl][m4 + 3] = bf2f(u.w);
        }
        __syncthreads();
        #pragma unroll
        for (int kk = 0; kk < 28; ++kk) {
            float4 a4 = *(float4*)&As[kk][tr * 4];
            float4 b4 = *(float4*)&Bs[kk][tc * 4];
            float aa[4] = {a4.x, a4.y, a4.z, a4.w};
            float wb[4] = {b4.x, b4.y, b4.z, b4.w};
            #pragma unroll
            for (int i = 0; i < 4; ++i)
                #pragma unroll
                for (int j = 0; j < 4; ++j)
                    acc[i][j] = fmaf(aa[i], wb[j], acc[i][j]);
        }
        __syncthreads();
    }
    #pragma unroll
    for (int i = 0; i < 4; ++i) {
        const int s = s0 + tr * 4 + i;
        if (s < Sn) {
            ushort4 o;
            o.x = f2bf(acc[i][0]); o.y = f2bf(acc[i][1]);
            o.z = f2bf(acc[i][2]); o.w = f2bf(acc[i][3]);
            *(ushort4*)&att[((size_t)b * Sn + s) * Mn + m0 + tc * 4] = o;
        }
    }
}

// ---- v2s[b,s] += sum_c (pool + bo + att@Wo)[b,s,c] * V[s,c]  (MFMA) ----
// rows = Bn*Sn = 39936 (tile 128), cols = Cn (tile 128), K = Mn, BK = 32
__global__ __launch_bounds__(256, 2) void k_out_mfma(
        const ushort* __restrict__ att, const ushort* __restrict__ woh,
        const float* __restrict__ bo, const float* __restrict__ pool,
        const float* __restrict__ Vf, float* __restrict__ out) {
    __shared__ __align__(16) ushort sA[128 * 32], sB[128 * 32];
    const int tid = threadIdx.x, lane = tid & 63, wid = tid >> 6;
    const size_t r0 = (size_t)blockIdx.y * 128;
    const int c0 = blockIdx.x * 128;

    f32x4 acc[4][4];
    #pragma unroll
    for (int i = 0; i < 4; ++i)
        #pragma unroll
        for (int j = 0; j < 4; ++j) acc[i][j] = (f32x4)0.f;

    const int fmb = (wid >> 1) * 4, fnb = (wid & 1) * 4;

    for (int k0 = 0; k0 < Mn; k0 += 32) {
        stage_tile(sA, att, r0, k0, Mn, tid);
        stage_tile(sB, woh, c0, k0, Mn, tid);
        __syncthreads();
        bf16x8 a[4], b[4];
        #pragma unroll
        for (int i = 0; i < 4; ++i) a[i] = frag_ld(sA, fmb + i, lane);
        #pragma unroll
        for (int j = 0; j < 4; ++j) b[j] = frag_ld(sB, fnb + j, lane);
        #pragma unroll
        for (int i = 0; i < 4; ++i)
            #pragma unroll
            for (int j = 0; j < 4; ++j)
                acc[i][j] = __builtin_amdgcn_mfma_f32_16x16x32_bf16(a[i], b[j], acc[i][j], 0, 0, 0);
        __syncthreads();
    }

    const int rw = (wid >> 1) * 64;
    const int cwb = c0 + (wid & 1) * 64;
    #pragma unroll
    for (int i = 0; i < 4; ++i) {
        #pragma unroll
        for (int rr = 0; rr < 4; ++rr) {
            const size_t row = r0 + rw + i * 16 + (lane >> 4) * 4 + rr;
            const int b_ = (int)(row / Sn);
            const int s_ = (int)(row - (size_t)b_ * Sn);
            float part = 0.f;
            #pragma unroll
            for (int j = 0; j < 4; ++j) {
                const int c = cwb + j * 16 + (lane & 15);
                const float fin = acc[i][j][rr] + pool[(size_t)b_ * Cn + c] + bo[c];
                part = fmaf(fin, Vf[(size_t)s_ * Cn + c], part);
            }
            #pragma unroll
            for (int mm = 1; mm < 16; mm <<= 1) part += __shfl_xor(part, mm);
            if ((lane & 15) == 0) atomicAdd(&out[row], part);
        }
    }
}

extern "C" void kernel_launch(void* const* d_in, const int* in_sizes, int n_in,
                              void* d_out, int out_size, void* d_ws, size_t ws_size,
                              hipStream_t stream) {
    (void)in_sizes; (void)n_in; (void)ws_size;
    const float* feat = (const float*)d_in[0];
    const float* w2v  = (const float*)d_in[1];
    const float* Wq   = (const float*)d_in[2];
    const float* bq   = (const float*)d_in[3];
    const float* Wk   = (const float*)d_in[4];
    const float* bk   = (const float*)d_in[5];
    const float* Wv   = (const float*)d_in[6];
    const float* bv   = (const float*)d_in[7];
    const float* Wo   = (const float*)d_in[8];
    const float* bo   = (const float*)d_in[9];
    const float* Vf   = (const float*)d_in[10];
    float* out = (float*)d_out;
    float* ws  = (float*)d_ws;

    float*  q_buf = ws + OFF_Q;
    float*  pool  = ws + OFF_POOL;
    float*  key   = ws + OFF_KEY;
    ushort* valb  = (ushort*)(ws + OFF_VALB);
    ushort* fhi   = (ushort*)(ws + OFF_FT);
    ushort* flo   = fhi + (size_t)Bn * Nn * Cn;
    float*  attn  = ws + OFF_ATTN;
    ushort* attb  = (ushort*)(ws + OFF_ATTB);
    ushort* wkh   = (ushort*)(ws + OFF_WKH);
    ushort* wkl   = (ushort*)(ws + OFF_WKL);
    ushort* wvh   = (ushort*)(ws + OFF_WVH);
    ushort* woh   = (ushort*)(ws + OFF_WOH);

    hipMemsetAsync(d_out, 0, (size_t)out_size * sizeof(float), stream);

    k_query <<<dim3(Sn, Mn / 256), 256, 0, stream>>>(w2v, Wq, bq, q_buf);
    k_pool  <<<dim3((Bn * Cn) / 4), 256, 0, stream>>>(feat, pool);
    k_prep_feat <<<dim3(Bn, Cn / 64), 256, 0, stream>>>(feat, fhi, flo);
    k_transpose_cvt <<<dim3(Mn / 64, Cn / 64), 256, 0, stream>>>(Wk, wkh, wkl, Cn, Mn);
    k_transpose_cvt <<<dim3(Mn / 64, Cn / 64), 256, 0, stream>>>(Wv, wvh, nullptr, Cn, Mn);
    k_transpose_cvt <<<dim3(Cn / 64, Mn / 64), 256, 0, stream>>>(Wo, woh, nullptr, Mn, Cn);

    k_kv_mfma <<<dim3(Mn / 128, (Bn * Nn) / 128), 256, 0, stream>>>(
        fhi, flo, wkh, wkl, wvh, bk, bv, key, valb);
    k_scores <<<dim3((Sn + 63) / 64, Bn), 256, 0, stream>>>(q_buf, key, attn);
    k_pv <<<dim3(Mn / 64, (Sn + 63) / 64, Bn), 256, 0, stream>>>(attn, valb, attb);
    k_out_mfma <<<dim3(Cn / 128, (Bn * Sn) / 128), 256, 0, stream>>>(
        attb, woh, bo, pool, Vf, out);
}

// Round 3
// 563.261 us; speedup vs baseline: 11.2384x; 4.2464x over previous
//
#include <hip/hip_runtime.h>
#include <hip/hip_bf16.h>

namespace {
constexpr int Bn = 128, Cn = 2048, Nn = 196, Sn = 312, Ln = 300, Mn = 1024;
constexpr int Sp = 320;  // padded S (5 * 64)
// f32-unit workspace offsets
constexpr size_t OFF_FHI  = 0;                                  // [Bn*Nn][Cn] bf16
constexpr size_t OFF_FLO  = OFF_FHI + (size_t)Bn*Nn*Cn/2;
constexpr size_t OFF_PH   = OFF_FLO + (size_t)Bn*Nn*Cn/2;       // poolh [Bn][Cn] bf16
constexpr size_t OFF_Q    = OFF_PH  + (size_t)Bn*Cn/2;          // q f32 [Sn][Mn]
constexpr size_t OFF_QH   = OFF_Q   + (size_t)Sn*Mn;            // [Sp][Mn] bf16
constexpr size_t OFF_QL   = OFF_QH  + (size_t)Sp*Mn/2;
constexpr size_t OFF_VH   = OFF_QL  + (size_t)Sp*Mn/2;          // [Sp][Cn] bf16
constexpr size_t OFF_WKH  = OFF_VH  + (size_t)Sp*Cn/2;          // [Cn][Mn] bf16
constexpr size_t OFF_WKL  = OFF_WKH + (size_t)Cn*Mn/2;
constexpr size_t OFF_WOB  = OFF_WKL + (size_t)Cn*Mn/2;          // [Mn][Cn] bf16
constexpr size_t OFF_WVB  = OFF_WOB + (size_t)Mn*Cn/2;          // [Cn][Mn] bf16
constexpr size_t OFF_QK   = OFF_WVB + (size_t)Cn*Mn/2;          // qk f32 [Sp][Cn]
constexpr size_t OFF_QKH  = OFF_QK  + (size_t)Sp*Cn;
constexpr size_t OFF_QKL  = OFF_QKH + (size_t)Sp*Cn/2;
constexpr size_t OFF_WVM  = OFF_QKL + (size_t)Sp*Cn/2;          // WV f32 [Sp][Mn]
constexpr size_t OFF_WVMH = OFF_WVM + (size_t)Sp*Mn;
constexpr size_t OFF_WWT  = OFF_WVMH+ (size_t)Sp*Mn/2;          // WWt f32 [Sp][Cn]
constexpr size_t OFF_WWTH = OFF_WWT + (size_t)Sp*Cn;
constexpr size_t OFF_PV   = OFF_WWTH+ (size_t)Sp*Cn/2;          // pv f32 [Bn][Sp]
constexpr size_t OFF_CST  = OFF_PV  + (size_t)Bn*Sp;            // cst f32 [Sn]
// total ~59.5M f32 = 238 MB (R1 used 403 MB successfully)
}

typedef __attribute__((ext_vector_type(8))) short bf16x8;
typedef __attribute__((ext_vector_type(4))) float f32x4;

__device__ __forceinline__ ushort f2bf(float x) {
    __hip_bfloat16 b = __float2bfloat16(x);
    return *reinterpret_cast<ushort*>(&b);
}
__device__ __forceinline__ float bf2f(ushort u) {
    __hip_bfloat16 b;
    *reinterpret_cast<ushort*>(&b) = u;
    return __bfloat162float(b);
}

__device__ __forceinline__ void gload16(void* lds, const void* g) {
    __builtin_amdgcn_global_load_lds(
        (const __attribute__((address_space(1))) void*)g,
        (__attribute__((address_space(3))) void*)lds, 16, 0, 0);
}

// Stage a [rows x 32] bf16 tile (nslots = rows*4 16B-slots). LDS linear; the
// XOR swizzle (chunk ^= (row>>1)&3) is applied on the SOURCE address so the
// matching swizzled frag_ld reads are conflict-free (2-way max = free).
__device__ __forceinline__ void stage_rows(ushort* lds, const ushort* src,
                                           size_t row0, int k0, int ld,
                                           int tid, int nslots) {
    int base = 0;
    for (; base + 256 <= nslots; base += 256) {
        const int slot = base + tid;
        const int r = slot >> 2, q = (slot & 3) ^ ((r >> 1) & 3);
        gload16(lds + (size_t)(base + (tid & 192)) * 8,
                src + (row0 + r) * (size_t)ld + k0 + q * 8);
    }
    const int rem = nslots - base;
    if (rem && tid < rem) {
        const int slot = base + tid;
        const int r = slot >> 2, q = (slot & 3) ^ ((r >> 1) & 3);
        gload16(lds + (size_t)base * 8,
                src + (row0 + r) * (size_t)ld + k0 + q * 8);
    }
}

// read one 16x32 fragment (lane l: row = fr*16 + (l&15), k-chunk = l>>4)
__device__ __forceinline__ bf16x8 frag_ld(const ushort* tile, int fr, int lane) {
    const int rl = lane & 15;
    const int q  = (lane >> 4) ^ ((rl >> 1) & 3);
    return *(const bf16x8*)(tile + ((fr * 16 + rl) * 32 + q * 8));
}

// ---------------- query = w2v @ Wq + bq : [Sn, Mn] f32 ----------------
__global__ __launch_bounds__(256) void k_query(
        const float* __restrict__ w2v, const float* __restrict__ Wq,
        const float* __restrict__ bq, float* __restrict__ qout) {
    __shared__ float a[Ln];
    const int s = blockIdx.x;
    const int m = blockIdx.y * 256 + threadIdx.x;
    for (int i = threadIdx.x; i < Ln; i += 256) a[i] = w2v[(size_t)s * Ln + i];
    __syncthreads();
    float acc = bq[m];
    #pragma unroll 4
    for (int k = 0; k < Ln; ++k) acc = fmaf(a[k], Wq[(size_t)k * Mn + m], acc);
    qout[(size_t)s * Mn + m] = acc;
}

// ---- feat[b][c][n] -> fhi/flo[(b*196+n)][c] (bf16 split) + poolh[b][c] ----
__global__ __launch_bounds__(256) void k_prep_feat(
        const float* __restrict__ feat, ushort* __restrict__ fhi,
        ushort* __restrict__ flo, ushort* __restrict__ poolh) {
    __shared__ float t[64][197];
    __shared__ float pp[64][4];
    const int b = blockIdx.x, c0 = blockIdx.y * 64;
    const int tid = threadIdx.x;
    for (int idx = tid; idx < 64 * Nn; idx += 256) {
        const int r = idx / Nn, n = idx - r * Nn;
        t[r][n] = feat[((size_t)b * Cn + c0 + r) * Nn + n];
    }
    __syncthreads();
    {   // pool partials: 4 threads per c, 49 n each
        const int c = tid >> 2, q = tid & 3;
        float s = 0.f;
        #pragma unroll
        for (int n = 0; n < 49; ++n) s += t[c][q * 49 + n];
        pp[c][q] = s;
    }
    for (int idx = tid; idx < Nn * 64; idx += 256) {
        const int n = idx >> 6, c = idx & 63;
        const float v = t[c][n];
        const ushort h = f2bf(v);
        const size_t o = ((size_t)b * Nn + n) * Cn + c0 + c;
        fhi[o] = h;
        flo[o] = f2bf(v - bf2f(h));
    }
    __syncthreads();
    if (tid < 64)
        poolh[(size_t)b * Cn + c0 + tid] =
            f2bf((pp[tid][0] + pp[tid][1] + pp[tid][2] + pp[tid][3]) * (1.0f / Nn));
}

// ---- cvt f32 [R][K] -> bf16 hi (+lo) [Rpad][K], pad rows zero ----
__global__ __launch_bounds__(256) void k_cvt(
        const float* __restrict__ in, ushort* __restrict__ hi,
        ushort* __restrict__ lo, int R, int Rpad, int K) {
    const size_t idx = ((size_t)blockIdx.x * 256 + threadIdx.x) * 4;
    if (idx >= (size_t)Rpad * K) return;
    const int r = (int)(idx / K);
    float4 v = make_float4(0.f, 0.f, 0.f, 0.f);
    if (r < R) v = *(const float4*)&in[idx];
    ushort4 h;
    h.x = f2bf(v.x); h.y = f2bf(v.y); h.z = f2bf(v.z); h.w = f2bf(v.w);
    *(ushort4*)&hi[idx] = h;
    if (lo) {
        ushort4 l;
        l.x = f2bf(v.x - bf2f(h.x)); l.y = f2bf(v.y - bf2f(h.y));
        l.z = f2bf(v.z - bf2f(h.z)); l.w = f2bf(v.w - bf2f(h.w));
        *(ushort4*)&lo[idx] = l;
    }
}

// ---- mini GEMM: out[r][c] = sum_k A[r][k]*B[c][k], 64x64 tile, 1-pass bf16 ----
__global__ __launch_bounds__(256) void k_mini(
        const ushort* __restrict__ A, const ushort* __restrict__ B,
        float* __restrict__ out, int K, int Cout) {
    __shared__ __align__(16) ushort sA[64 * 32], sB[64 * 32];
    const int tid = threadIdx.x, lane = tid & 63, wid = tid >> 6;
    const size_t r0 = (size_t)blockIdx.y * 64;
    const int c0 = blockIdx.x * 64;
    f32x4 acc[2][2];
    #pragma unroll
    for (int i = 0; i < 2; ++i)
        #pragma unroll
        for (int j = 0; j < 2; ++j) acc[i][j] = (f32x4)0.f;
    const int fa = (wid >> 1) * 2, fb = (wid & 1) * 2;
    for (int k0 = 0; k0 < K; k0 += 32) {
        stage_rows(sA, A, r0, k0, K, tid, 256);
        stage_rows(sB, B, c0, k0, K, tid, 256);
        __syncthreads();
        bf16x8 a0 = frag_ld(sA, fa, lane), a1 = frag_ld(sA, fa + 1, lane);
        bf16x8 b0 = frag_ld(sB, fb, lane), b1 = frag_ld(sB, fb + 1, lane);
        acc[0][0] = __builtin_amdgcn_mfma_f32_16x16x32_bf16(a0, b0, acc[0][0], 0, 0, 0);
        acc[0][1] = __builtin_amdgcn_mfma_f32_16x16x32_bf16(a0, b1, acc[0][1], 0, 0, 0);
        acc[1][0] = __builtin_amdgcn_mfma_f32_16x16x32_bf16(a1, b0, acc[1][0], 0, 0, 0);
        acc[1][1] = __builtin_amdgcn_mfma_f32_16x16x32_bf16(a1, b1, acc[1][1], 0, 0, 0);
        __syncthreads();
    }
    #pragma unroll
    for (int i = 0; i < 2; ++i)
        #pragma unroll
        for (int j = 0; j < 2; ++j)
            #pragma unroll
            for (int rr = 0; rr < 4; ++rr) {
                const size_t row = r0 + (wid >> 1) * 32 + i * 16 + (lane >> 4) * 4 + rr;
                const int col = c0 + (wid & 1) * 32 + j * 16 + (lane & 15);
                out[row * Cout + col] = acc[i][j][rr];
            }
}

// ---- mini GEMM, split-bf16 3-pass (for qk = q @ Wk^T) ----
__global__ __launch_bounds__(256) void k_mini3(
        const ushort* __restrict__ Ah, const ushort* __restrict__ Al,
        const ushort* __restrict__ Bh, const ushort* __restrict__ Bl,
        float* __restrict__ out, int K, int Cout) {
    __shared__ __align__(16) ushort sAh[64 * 32], sAl[64 * 32];
    __shared__ __align__(16) ushort sBh[64 * 32], sBl[64 * 32];
    const int tid = threadIdx.x, lane = tid & 63, wid = tid >> 6;
    const size_t r0 = (size_t)blockIdx.y * 64;
    const int c0 = blockIdx.x * 64;
    f32x4 acc[2][2];
    #pragma unroll
    for (int i = 0; i < 2; ++i)
        #pragma unroll
        for (int j = 0; j < 2; ++j) acc[i][j] = (f32x4)0.f;
    const int fa = (wid >> 1) * 2, fb = (wid & 1) * 2;
    for (int k0 = 0; k0 < K; k0 += 32) {
        stage_rows(sAh, Ah, r0, k0, K, tid, 256);
        stage_rows(sAl, Al, r0, k0, K, tid, 256);
        stage_rows(sBh, Bh, c0, k0, K, tid, 256);
        stage_rows(sBl, Bl, c0, k0, K, tid, 256);
        __syncthreads();
        #pragma unroll
        for (int i = 0; i < 2; ++i) {
            const bf16x8 ah = frag_ld(sAh, fa + i, lane);
            const bf16x8 al = frag_ld(sAl, fa + i, lane);
            #pragma unroll
            for (int j = 0; j < 2; ++j) {
                const bf16x8 bh = frag_ld(sBh, fb + j, lane);
                const bf16x8 bl = frag_ld(sBl, fb + j, lane);
                acc[i][j] = __builtin_amdgcn_mfma_f32_16x16x32_bf16(ah, bh, acc[i][j], 0, 0, 0);
                acc[i][j] = __builtin_amdgcn_mfma_f32_16x16x32_bf16(ah, bl, acc[i][j], 0, 0, 0);
                acc[i][j] = __builtin_amdgcn_mfma_f32_16x16x32_bf16(al, bh, acc[i][j], 0, 0, 0);
            }
        }
        __syncthreads();
    }
    #pragma unroll
    for (int i = 0; i < 2; ++i)
        #pragma unroll
        for (int j = 0; j < 2; ++j)
            #pragma unroll
            for (int rr = 0; rr < 4; ++rr) {
                const size_t row = r0 + (wid >> 1) * 32 + i * 16 + (lane >> 4) * 4 + rr;
                const int col = c0 + (wid & 1) * 32 + j * 16 + (lane & 15);
                out[row * Cout + col] = acc[i][j][rr];
            }
}

// ---- cst[s] = bo.V[s] + bv.WV[s] ----
__global__ __launch_bounds__(256) void k_cst(
        const float* __restrict__ bo, const float* __restrict__ Vf,
        const float* __restrict__ bv, const float* __restrict__ WVm,
        float* __restrict__ cst) {
    const int lane = threadIdx.x & 63, wid = threadIdx.x >> 6;
    const int s = blockIdx.x * 4 + wid;
    if (s >= Sn) return;
    float part = 0.f;
    for (int c = lane; c < Cn; c += 64) part = fmaf(bo[c], Vf[(size_t)s * Cn + c], part);
    for (int m = lane; m < Mn; m += 64) part = fmaf(bv[m], WVm[(size_t)s * Mn + m], part);
    #pragma unroll
    for (int mm = 32; mm; mm >>= 1) part += __shfl_xor(part, mm);
    if (lane == 0) cst[s] = part;
}

// ---- THE fused kernel: scores (3-pass) + VWc (1-pass) + softmax + contract ----
// grid (s-tile 5, b 128); block 256 = 4 waves x 16 s-rows; n = 208 (13 frags)
__global__ __launch_bounds__(256, 2) void k_attn(
        const ushort* __restrict__ fhi, const ushort* __restrict__ flo,
        const ushort* __restrict__ qkh, const ushort* __restrict__ qkl,
        const ushort* __restrict__ wwth, const float* __restrict__ pvb,
        const float* __restrict__ cst, float* __restrict__ out) {
    __shared__ __align__(16) ushort sFh[208 * 32], sFl[208 * 32];
    __shared__ __align__(16) ushort sQh[64 * 32], sQl[64 * 32], sW[64 * 32];
    const int tid = threadIdx.x, lane = tid & 63, wid = tid >> 6;
    const int s0 = blockIdx.x * 64;
    const int b  = blockIdx.y;
    const size_t frow0 = (size_t)b * Nn;

    f32x4 sc[13], vw[13];
    #pragma unroll
    for (int j = 0; j < 13; ++j) { sc[j] = (f32x4)0.f; vw[j] = (f32x4)0.f; }

    for (int k0 = 0; k0 < Cn; k0 += 32) {
        stage_rows(sFh, fhi, frow0, k0, Cn, tid, 832);
        stage_rows(sFl, flo, frow0, k0, Cn, tid, 832);
        stage_rows(sQh, qkh, s0, k0, Cn, tid, 256);
        stage_rows(sQl, qkl, s0, k0, Cn, tid, 256);
        stage_rows(sW, wwth, s0, k0, Cn, tid, 256);
        __syncthreads();
        const bf16x8 qh = frag_ld(sQh, wid, lane);
        const bf16x8 ql = frag_ld(sQl, wid, lane);
        const bf16x8 wt = frag_ld(sW, wid, lane);
        #pragma unroll
        for (int j = 0; j < 13; ++j) {
            const bf16x8 fh = frag_ld(sFh, j, lane);
            const bf16x8 fl = frag_ld(sFl, j, lane);
            sc[j] = __builtin_amdgcn_mfma_f32_16x16x32_bf16(qh, fh, sc[j], 0, 0, 0);
            sc[j] = __builtin_amdgcn_mfma_f32_16x16x32_bf16(qh, fl, sc[j], 0, 0, 0);
            sc[j] = __builtin_amdgcn_mfma_f32_16x16x32_bf16(ql, fh, sc[j], 0, 0, 0);
            vw[j] = __builtin_amdgcn_mfma_f32_16x16x32_bf16(wt, fh, vw[j], 0, 0, 0);
        }
        __syncthreads();
    }

    // per-row softmax over n (cols distributed on 16-lane groups) + contraction
    const int g = lane & 15;
    #pragma unroll
    for (int rr = 0; rr < 4; ++rr) {
        float mx = -1e30f;
        #pragma unroll
        for (int j = 0; j < 13; ++j)
            if (j < 12 || g < 4) mx = fmaxf(mx, sc[j][rr]);
        #pragma unroll
        for (int mm = 1; mm < 16; mm <<= 1) mx = fmaxf(mx, __shfl_xor(mx, mm));
        float den = 0.f, num = 0.f;
        #pragma unroll
        for (int j = 0; j < 13; ++j)
            if (j < 12 || g < 4) {
                const float e = __expf(sc[j][rr] - mx);
                den += e;
                num = fmaf(e, vw[j][rr], num);
            }
        #pragma unroll
        for (int mm = 1; mm < 16; mm <<= 1) {
            den += __shfl_xor(den, mm);
            num += __shfl_xor(num, mm);
        }
        if (g == 0) {
            const int s = s0 + wid * 16 + (lane >> 4) * 4 + rr;
            if (s < Sn)
                out[(size_t)b * Sn + s] = pvb[(size_t)b * Sp + s] + cst[s] + num / den;
        }
    }
}

extern "C" void kernel_launch(void* const* d_in, const int* in_sizes, int n_in,
                              void* d_out, int out_size, void* d_ws, size_t ws_size,
                              hipStream_t stream) {
    (void)in_sizes; (void)n_in; (void)ws_size; (void)out_size;
    const float* feat = (const float*)d_in[0];
    const float* w2v  = (const float*)d_in[1];
    const float* Wq   = (const float*)d_in[2];
    const float* bq   = (const float*)d_in[3];
    const float* Wk   = (const float*)d_in[4];
    const float* Wv   = (const float*)d_in[6];
    const float* bv   = (const float*)d_in[7];
    const float* Wo   = (const float*)d_in[8];
    const float* bo   = (const float*)d_in[9];
    const float* Vf   = (const float*)d_in[10];
    float* out = (float*)d_out;
    float* ws  = (float*)d_ws;

    ushort* fhi  = (ushort*)(ws + OFF_FHI);
    ushort* flo  = (ushort*)(ws + OFF_FLO);
    ushort* ph   = (ushort*)(ws + OFF_PH);
    float*  q    = ws + OFF_Q;
    ushort* qh   = (ushort*)(ws + OFF_QH);
    ushort* ql   = (ushort*)(ws + OFF_QL);
    ushort* vh   = (ushort*)(ws + OFF_VH);
    ushort* wkh  = (ushort*)(ws + OFF_WKH);
    ushort* wkl  = (ushort*)(ws + OFF_WKL);
    ushort* wob  = (ushort*)(ws + OFF_WOB);
    ushort* wvb  = (ushort*)(ws + OFF_WVB);
    float*  qk   = ws + OFF_QK;
    ushort* qkh  = (ushort*)(ws + OFF_QKH);
    ushort* qkl  = (ushort*)(ws + OFF_QKL);
    float*  wvm  = ws + OFF_WVM;
    ushort* wvmh = (ushort*)(ws + OFF_WVMH);
    float*  wwt  = ws + OFF_WWT;
    ushort* wwth = (ushort*)(ws + OFF_WWTH);
    float*  pvb  = ws + OFF_PV;
    float*  cst  = ws + OFF_CST;

    // feat transpose/split + pool
    k_prep_feat<<<dim3(Bn, Cn / 64), 256, 0, stream>>>(feat, fhi, flo, ph);
    // query f32
    k_query<<<dim3(Sn, Mn / 256), 256, 0, stream>>>(w2v, Wq, bq, q);
    // conversions
    k_cvt<<<(Sp * Mn) / 1024, 256, 0, stream>>>(q, qh, ql, Sn, Sp, Mn);
    k_cvt<<<(Sp * Cn) / 1024, 256, 0, stream>>>(Vf, vh, nullptr, Sn, Sp, Cn);
    k_cvt<<<(Cn * Mn) / 1024, 256, 0, stream>>>(Wk, wkh, wkl, Cn, Cn, Mn);
    k_cvt<<<(Mn * Cn) / 1024, 256, 0, stream>>>(Wo, wob, nullptr, Mn, Mn, Cn);
    k_cvt<<<(Cn * Mn) / 1024, 256, 0, stream>>>(Wv, wvb, nullptr, Cn, Cn, Mn);
    // qk = q @ Wk^T  (split 3-pass, [Sp][Cn])
    k_mini3<<<dim3(Cn / 64, Sp / 64), 256, 0, stream>>>(qh, ql, wkh, wkl, qk, Mn, Cn);
    k_cvt<<<(Sp * Cn) / 1024, 256, 0, stream>>>(qk, qkh, qkl, Sp, Sp, Cn);
    // WV = V @ Wo^T  ([Sp][Mn])
    k_mini<<<dim3(Mn / 64, Sp / 64), 256, 0, stream>>>(vh, wob, wvm, Cn, Mn);
    k_cvt<<<(Sp * Mn) / 1024, 256, 0, stream>>>(wvm, wvmh, nullptr, Sp, Sp, Mn);
    // WWt = WV @ Wv^T  ([Sp][Cn])
    k_mini<<<dim3(Cn / 64, Sp / 64), 256, 0, stream>>>(wvmh, wvb, wwt, Mn, Cn);
    k_cvt<<<(Sp * Cn) / 1024, 256, 0, stream>>>(wwt, wwth, nullptr, Sp, Sp, Cn);
    // pv = pool @ V^T  ([Bn][Sp])
    k_mini<<<dim3(Sp / 64, Bn / 64), 256, 0, stream>>>(ph, vh, pvb, Cn, Sp);
    // cst[s] = bo.V[s] + bv.WV[s]
    k_cst<<<(Sn + 3) / 4, 256, 0, stream>>>(bo, Vf, bv, wvm, cst);
    // fused scores + VWc + softmax + contraction -> out
    k_attn<<<dim3(Sp / 64, Bn), 256, 0, stream>>>(fhi, flo, qkh, qkl, wwth, pvb, cst, out);
}

// Round 4
// 357.851 us; speedup vs baseline: 17.6893x; 1.5740x over previous
//
#include <hip/hip_runtime.h>
#include <hip/hip_bf16.h>

namespace {
constexpr int Bn = 128, Cn = 2048, Nn = 196, Sn = 312, Ln = 300, Mn = 1024;
constexpr int Sp = 320;  // padded S (5 * 64)
// f32-unit workspace offsets
constexpr size_t OFF_F16  = 0;                                   // fT fp16 [Bn*Nn][Cn]
constexpr size_t OFF_PH   = OFF_F16 + (size_t)Bn*Nn*Cn/2;        // pool fp16 [Bn][Cn]
constexpr size_t OFF_Q    = OFF_PH  + (size_t)Bn*Cn/2;           // q f32 [Sn][Mn]
constexpr size_t OFF_Q16  = OFF_Q   + (size_t)Sn*Mn;             // [Sp][Mn]
constexpr size_t OFF_V16  = OFF_Q16 + (size_t)Sp*Mn/2;           // [Sp][Cn]
constexpr size_t OFF_WK16 = OFF_V16 + (size_t)Sp*Cn/2;           // [Cn][Mn]
constexpr size_t OFF_WO16 = OFF_WK16+ (size_t)Cn*Mn/2;           // [Mn][Cn]
constexpr size_t OFF_WV16 = OFF_WO16+ (size_t)Mn*Cn/2;           // [Cn][Mn]
constexpr size_t OFF_QK16 = OFF_WV16+ (size_t)Cn*Mn/2;           // [Sp][Cn]
constexpr size_t OFF_WVM16= OFF_QK16+ (size_t)Sp*Cn/2;           // [Sp][Mn]
constexpr size_t OFF_WWT16= OFF_WVM16+(size_t)Sp*Mn/2;           // [Sp][Cn]
constexpr size_t OFF_PV   = OFF_WWT16+(size_t)Sp*Cn/2;           // f32 [Bn][Sp]
constexpr size_t OFF_CST  = OFF_PV  + (size_t)Bn*Sp;             // f32 [Sp]
// total ~= 30.7M f32 ~= 123 MB (prior rounds used up to 403 MB fine)
}

typedef __attribute__((ext_vector_type(8))) short u16x8;
typedef __attribute__((ext_vector_type(8))) _Float16 f16x8;
typedef __attribute__((ext_vector_type(4))) _Float16 f16x4;
typedef __attribute__((ext_vector_type(4))) float f32x4;

__device__ __forceinline__ f16x8 as_h(u16x8 v) { return __builtin_bit_cast(f16x8, v); }

__device__ __forceinline__ void gload16(void* lds, const void* g) {
    __builtin_amdgcn_global_load_lds(
        (const __attribute__((address_space(1))) void*)g,
        (__attribute__((address_space(3))) void*)lds, 16, 0, 0);
}

// Stage a [rows x 32] fp16 tile (nslots = rows*4 16B-slots). LDS linear; the
// XOR swizzle (chunk ^= (row>>1)&3) is applied on the SOURCE address so the
// matching swizzled frag_ld reads are conflict-free (2-way max = free).
__device__ __forceinline__ void stage_rows(ushort* lds, const ushort* src,
                                           size_t row0, int k0, int ld,
                                           int tid, int nslots) {
    int base = 0;
    for (; base + 256 <= nslots; base += 256) {
        const int slot = base + tid;
        const int r = slot >> 2, q = (slot & 3) ^ ((r >> 1) & 3);
        gload16(lds + (size_t)(base + (tid & 192)) * 8,
                src + (row0 + r) * (size_t)ld + k0 + q * 8);
    }
    const int rem = nslots - base;
    if (rem && tid < rem) {
        const int slot = base + tid;
        const int r = slot >> 2, q = (slot & 3) ^ ((r >> 1) & 3);
        gload16(lds + (size_t)base * 8,
                src + (row0 + r) * (size_t)ld + k0 + q * 8);
    }
}

// read one 16x32 fragment (lane l: row = fr*16 + (l&15), k-chunk = l>>4)
__device__ __forceinline__ u16x8 frag_ld(const ushort* tile, int fr, int lane) {
    const int rl = lane & 15;
    const int q  = (lane >> 4) ^ ((rl >> 1) & 3);
    return *(const u16x8*)(tile + ((fr * 16 + rl) * 32 + q * 8));
}

// ---------------- query = w2v @ Wq + bq : [Sn, Mn] f32 ----------------
__global__ __launch_bounds__(256) void k_query(
        const float* __restrict__ w2v, const float* __restrict__ Wq,
        const float* __restrict__ bq, float* __restrict__ qout) {
    __shared__ float a[Ln];
    const int s = blockIdx.x;
    const int m = blockIdx.y * 256 + threadIdx.x;
    for (int i = threadIdx.x; i < Ln; i += 256) a[i] = w2v[(size_t)s * Ln + i];
    __syncthreads();
    float acc = bq[m];
    #pragma unroll 4
    for (int k = 0; k < Ln; ++k) acc = fmaf(a[k], Wq[(size_t)k * Mn + m], acc);
    qout[(size_t)s * Mn + m] = acc;
}

// ---- feat[b][c][n] -> f16[(b*196+n)][c] (fp16) + poolh[b][c] (fp16) ----
__global__ __launch_bounds__(256) void k_prep_feat(
        const float* __restrict__ feat, _Float16* __restrict__ f16,
        _Float16* __restrict__ poolh) {
    __shared__ float t[64][197];
    __shared__ float pp[64][4];
    const int b = blockIdx.x, c0 = blockIdx.y * 64;
    const int tid = threadIdx.x;
    for (int idx = tid; idx < 64 * 49; idx += 256) {
        const int r = idx / 49, nq = idx - r * 49;
        const float4 v = *(const float4*)&feat[((size_t)b * Cn + c0 + r) * Nn + nq * 4];
        t[r][nq * 4 + 0] = v.x; t[r][nq * 4 + 1] = v.y;
        t[r][nq * 4 + 2] = v.z; t[r][nq * 4 + 3] = v.w;
    }
    __syncthreads();
    {   // pool partials: 4 threads per c, 49 n each
        const int c = tid >> 2, q = tid & 3;
        float s = 0.f;
        #pragma unroll
        for (int n = 0; n < 49; ++n) s += t[c][q * 49 + n];
        pp[c][q] = s;
    }
    for (int idx = tid; idx < Nn * 32; idx += 256) {
        const int n = idx >> 5, cp = (idx & 31) * 2;
        f16x4 h;  // write 2 c's at once (4B store)
        h[0] = (_Float16)t[cp][n]; h[1] = (_Float16)t[cp + 1][n];
        *(uint*)&f16[((size_t)b * Nn + n) * Cn + c0 + cp] = __builtin_bit_cast(uint, *(uint*)&h);
    }
    __syncthreads();
    if (tid < 64)
        poolh[(size_t)b * Cn + c0 + tid] =
            (_Float16)((pp[tid][0] + pp[tid][1] + pp[tid][2] + pp[tid][3]) * (1.0f / Nn));
}

// ---- cvt f32 [R][K] -> fp16 [Rpad][K], pad rows zero ----
__global__ __launch_bounds__(256) void k_cvt_h(
        const float* __restrict__ in, _Float16* __restrict__ o,
        int R, int Rpad, int K) {
    const size_t idx = ((size_t)blockIdx.x * 256 + threadIdx.x) * 4;
    if (idx >= (size_t)Rpad * K) return;
    const int r = (int)(idx / K);
    float4 v = make_float4(0.f, 0.f, 0.f, 0.f);
    if (r < R) v = *(const float4*)&in[idx];
    f16x4 h;
    h[0] = (_Float16)v.x; h[1] = (_Float16)v.y;
    h[2] = (_Float16)v.z; h[3] = (_Float16)v.w;
    *(f16x4*)&o[idx] = h;
}

// ---- mini GEMM: out[r][c] = sum_k A[r][k]*B[c][k], 64x64 tile, fp16 MFMA ----
__global__ __launch_bounds__(256) void k_mini(
        const _Float16* __restrict__ A, const _Float16* __restrict__ B,
        float* __restrict__ outf, _Float16* __restrict__ outh, int K, int Cout) {
    __shared__ __align__(16) ushort sA[64 * 32], sB[64 * 32];
    const int tid = threadIdx.x, lane = tid & 63, wid = tid >> 6;
    const size_t r0 = (size_t)blockIdx.y * 64;
    const int c0 = blockIdx.x * 64;
    f32x4 acc[2][2];
    #pragma unroll
    for (int i = 0; i < 2; ++i)
        #pragma unroll
        for (int j = 0; j < 2; ++j) acc[i][j] = (f32x4)0.f;
    const int fa = (wid >> 1) * 2, fb = (wid & 1) * 2;
    for (int k0 = 0; k0 < K; k0 += 32) {
        stage_rows(sA, (const ushort*)A, r0, k0, K, tid, 256);
        stage_rows(sB, (const ushort*)B, c0, k0, K, tid, 256);
        __syncthreads();
        f16x8 a0 = as_h(frag_ld(sA, fa, lane)), a1 = as_h(frag_ld(sA, fa + 1, lane));
        f16x8 b0 = as_h(frag_ld(sB, fb, lane)), b1 = as_h(frag_ld(sB, fb + 1, lane));
        acc[0][0] = __builtin_amdgcn_mfma_f32_16x16x32_f16(a0, b0, acc[0][0], 0, 0, 0);
        acc[0][1] = __builtin_amdgcn_mfma_f32_16x16x32_f16(a0, b1, acc[0][1], 0, 0, 0);
        acc[1][0] = __builtin_amdgcn_mfma_f32_16x16x32_f16(a1, b0, acc[1][0], 0, 0, 0);
        acc[1][1] = __builtin_amdgcn_mfma_f32_16x16x32_f16(a1, b1, acc[1][1], 0, 0, 0);
        __syncthreads();
    }
    #pragma unroll
    for (int i = 0; i < 2; ++i)
        #pragma unroll
        for (int j = 0; j < 2; ++j)
            #pragma unroll
            for (int rr = 0; rr < 4; ++rr) {
                const size_t row = r0 + (wid >> 1) * 32 + i * 16 + (lane >> 4) * 4 + rr;
                const int col = c0 + (wid & 1) * 32 + j * 16 + (lane & 15);
                if (outh) outh[row * Cout + col] = (_Float16)acc[i][j][rr];
                else      outf[row * Cout + col] = acc[i][j][rr];
            }
}

// ---- cst[s] = bo.V[s] + bv.WV[s] ----
__global__ __launch_bounds__(256) void k_cst(
        const float* __restrict__ bo, const float* __restrict__ Vf,
        const float* __restrict__ bv, const _Float16* __restrict__ WVm,
        float* __restrict__ cst) {
    const int lane = threadIdx.x & 63, wid = threadIdx.x >> 6;
    const int s = blockIdx.x * 4 + wid;
    if (s >= Sn) return;
    float part = 0.f;
    for (int c = lane; c < Cn; c += 64) part = fmaf(bo[c], Vf[(size_t)s * Cn + c], part);
    for (int m = lane; m < Mn; m += 64) part = fmaf(bv[m], (float)WVm[(size_t)s * Mn + m], part);
    #pragma unroll
    for (int mm = 32; mm; mm >>= 1) part += __shfl_xor(part, mm);
    if (lane == 0) cst[s] = part;
}

// ---- fused: scores + VWc (fp16 MFMA) + softmax + contract -> out ----
// 640 blocks; XCD-swizzled so each b's 5 s-tiles share an XCD's L2.
__global__ __launch_bounds__(256) void k_attn(
        const _Float16* __restrict__ f16, const _Float16* __restrict__ qk16,
        const _Float16* __restrict__ ww16, const float* __restrict__ pvb,
        const float* __restrict__ cst, float* __restrict__ out) {
    __shared__ __align__(16) ushort sF[208 * 32];
    __shared__ __align__(16) ushort sQ[64 * 32], sW[64 * 32];
    const int tid = threadIdx.x, lane = tid & 63, wid = tid >> 6;
    const int id = blockIdx.x;
    const int xcd = id & 7, slot = id >> 3;
    const int b  = xcd * 16 + slot / 5;       // 5 sibling s-tiles -> same XCD
    const int s0 = (slot % 5) * 64;
    const size_t frow0 = (size_t)b * Nn;

    f32x4 sc[13], vw[13];
    #pragma unroll
    for (int j = 0; j < 13; ++j) { sc[j] = (f32x4)0.f; vw[j] = (f32x4)0.f; }

    for (int k0 = 0; k0 < Cn; k0 += 32) {
        stage_rows(sF, (const ushort*)f16, frow0, k0, Cn, tid, 832);
        stage_rows(sQ, (const ushort*)qk16, s0, k0, Cn, tid, 256);
        stage_rows(sW, (const ushort*)ww16, s0, k0, Cn, tid, 256);
        __syncthreads();
        const f16x8 qf = as_h(frag_ld(sQ, wid, lane));
        const f16x8 wf = as_h(frag_ld(sW, wid, lane));
        #pragma unroll
        for (int j = 0; j < 13; ++j) {
            const f16x8 ff = as_h(frag_ld(sF, j, lane));
            sc[j] = __builtin_amdgcn_mfma_f32_16x16x32_f16(qf, ff, sc[j], 0, 0, 0);
            vw[j] = __builtin_amdgcn_mfma_f32_16x16x32_f16(wf, ff, vw[j], 0, 0, 0);
        }
        __syncthreads();
    }

    // per-row softmax over n (cols on 16-lane groups) + contraction
    const int g = lane & 15;
    #pragma unroll
    for (int rr = 0; rr < 4; ++rr) {
        float mx = -1e30f;
        #pragma unroll
        for (int j = 0; j < 13; ++j)
            if (j < 12 || g < 4) mx = fmaxf(mx, sc[j][rr]);
        #pragma unroll
        for (int mm = 1; mm < 16; mm <<= 1) mx = fmaxf(mx, __shfl_xor(mx, mm));
        float den = 0.f, num = 0.f;
        #pragma unroll
        for (int j = 0; j < 13; ++j)
            if (j < 12 || g < 4) {
                const float e = __expf(sc[j][rr] - mx);
                den += e;
                num = fmaf(e, vw[j][rr], num);
            }
        #pragma unroll
        for (int mm = 1; mm < 16; mm <<= 1) {
            den += __shfl_xor(den, mm);
            num += __shfl_xor(num, mm);
        }
        if (g == 0) {
            const int s = s0 + wid * 16 + (lane >> 4) * 4 + rr;
            if (s < Sn)
                out[(size_t)b * Sn + s] = pvb[(size_t)b * Sp + s] + cst[s] + num / den;
        }
    }
}

extern "C" void kernel_launch(void* const* d_in, const int* in_sizes, int n_in,
                              void* d_out, int out_size, void* d_ws, size_t ws_size,
                              hipStream_t stream) {
    (void)in_sizes; (void)n_in; (void)ws_size; (void)out_size;
    const float* feat = (const float*)d_in[0];
    const float* w2v  = (const float*)d_in[1];
    const float* Wq   = (const float*)d_in[2];
    const float* bq   = (const float*)d_in[3];
    const float* Wk   = (const float*)d_in[4];
    const float* Wv   = (const float*)d_in[6];
    const float* bv   = (const float*)d_in[7];
    const float* Wo   = (const float*)d_in[8];
    const float* bo   = (const float*)d_in[9];
    const float* Vf   = (const float*)d_in[10];
    float* out = (float*)d_out;
    float* ws  = (float*)d_ws;

    _Float16* f16   = (_Float16*)(ws + OFF_F16);
    _Float16* ph    = (_Float16*)(ws + OFF_PH);
    float*    q     = ws + OFF_Q;
    _Float16* q16   = (_Float16*)(ws + OFF_Q16);
    _Float16* v16   = (_Float16*)(ws + OFF_V16);
    _Float16* wk16  = (_Float16*)(ws + OFF_WK16);
    _Float16* wo16  = (_Float16*)(ws + OFF_WO16);
    _Float16* wv16  = (_Float16*)(ws + OFF_WV16);
    _Float16* qk16  = (_Float16*)(ws + OFF_QK16);
    _Float16* wvm16 = (_Float16*)(ws + OFF_WVM16);
    _Float16* wwt16 = (_Float16*)(ws + OFF_WWT16);
    float*    pvb   = ws + OFF_PV;
    float*    cst   = ws + OFF_CST;

    // feat transpose -> fp16 + pool
    k_prep_feat<<<dim3(Bn, Cn / 64), 256, 0, stream>>>(feat, f16, ph);
    // query f32
    k_query<<<dim3(Sn, Mn / 256), 256, 0, stream>>>(w2v, Wq, bq, q);
    // fp16 conversions
    k_cvt_h<<<(Sp * Mn) / 1024, 256, 0, stream>>>(q, q16, Sn, Sp, Mn);
    k_cvt_h<<<(Sp * Cn) / 1024, 256, 0, stream>>>(Vf, v16, Sn, Sp, Cn);
    k_cvt_h<<<(Cn * Mn) / 1024, 256, 0, stream>>>(Wk, wk16, Cn, Cn, Mn);
    k_cvt_h<<<(Mn * Cn) / 1024, 256, 0, stream>>>(Wo, wo16, Mn, Mn, Cn);
    k_cvt_h<<<(Cn * Mn) / 1024, 256, 0, stream>>>(Wv, wv16, Cn, Cn, Mn);
    // qk = q @ Wk^T  [Sp][Cn] fp16
    k_mini<<<dim3(Cn / 64, Sp / 64), 256, 0, stream>>>(q16, wk16, nullptr, qk16, Mn, Cn);
    // WV = V @ Wo^T  [Sp][Mn] fp16
    k_mini<<<dim3(Mn / 64, Sp / 64), 256, 0, stream>>>(v16, wo16, nullptr, wvm16, Cn, Mn);
    // WWt = WV @ Wv^T  [Sp][Cn] fp16
    k_mini<<<dim3(Cn / 64, Sp / 64), 256, 0, stream>>>(wvm16, wv16, nullptr, wwt16, Mn, Cn);
    // pv = pool @ V^T  [Bn][Sp] f32
    k_mini<<<dim3(Sp / 64, Bn / 64), 256, 0, stream>>>(ph, v16, pvb, nullptr, Cn, Sp);
    // cst[s] = bo.V[s] + bv.WV[s]
    k_cst<<<(Sn + 3) / 4, 256, 0, stream>>>(bo, Vf, bv, wvm16, cst);
    // fused attention -> out
    k_attn<<<dim3(640), 256, 0, stream>>>(f16, qk16, wwt16, pvb, cst, out);
}

// Round 7
// 247.804 us; speedup vs baseline: 25.5449x; 1.4441x over previous
//
#include <hip/hip_runtime.h>
#include <hip/hip_bf16.h>

namespace {
constexpr int Bn = 128, Cn = 2048, Nn = 196, Sn = 312, Ln = 300, Mn = 1024;
constexpr int Sp = 320, Lp = 320, PR = 192;

// f32-unit workspace offsets (all multiples of 4 f32 = 16 B)
constexpr size_t OFF_F16   = 0;                                  // fT fp16 [Bn*Nn][Cn]
constexpr size_t OFF_POOLX = OFF_F16   + (size_t)Bn*Nn*Cn/2;     // fp16 [PR][Cn] (rows 0-127 pool, 128 bo+bvo)
constexpr size_t OFF_HC    = OFF_POOLX + (size_t)PR*Cn/2;        // fp16 [Cn][Lp]  Hc[c][l] = sum_m Wk[c,m]Wq[l,m]
constexpr size_t OFF_WVM   = OFF_HC    + (size_t)Cn*Lp/2;        // fp16 [Sp][Mn]  WV = V @ Wo^T
constexpr size_t OFF_V16   = OFF_WVM   + (size_t)Sp*Mn/2;        // fp16 [Sp][Cn]
constexpr size_t OFF_WV16  = OFF_V16   + (size_t)Sp*Cn/2;        // fp16 [Cn][Mn]
constexpr size_t OFF_W2V   = OFF_WV16  + (size_t)Cn*Mn/2;        // fp16 [Sp][Lp]
constexpr size_t OFF_BQK   = OFF_W2V   + (size_t)Sp*Lp/2;        // f32 [Cn]  bq @ Wk^T
constexpr size_t OFF_QK    = OFF_BQK   + Cn;                     // fp16 [Sp][Cn]
constexpr size_t OFF_WWT   = OFF_QK    + (size_t)Sp*Cn/2;        // fp16 [Sp][Cn]
constexpr size_t OFF_PVF   = OFF_WWT   + (size_t)Sp*Cn/2;        // f32 [PR][Sp] (row b = pool.V, row 128 = cst)
}

typedef __attribute__((ext_vector_type(8))) short u16x8;
typedef __attribute__((ext_vector_type(8))) _Float16 f16x8;
typedef __attribute__((ext_vector_type(4))) _Float16 f16x4;
typedef __attribute__((ext_vector_type(4))) float f32x4;

__device__ __forceinline__ f16x8 as_h(u16x8 v) { return __builtin_bit_cast(f16x8, v); }

__device__ __forceinline__ void gload16(void* lds, const void* g) {
    __builtin_amdgcn_global_load_lds(
        (const __attribute__((address_space(1))) void*)g,
        (__attribute__((address_space(3))) void*)lds, 16, 0, 0);
}

// Stage a [rows x 32] fp16 tile (nslots = rows*4 16B-slots). LDS linear; XOR
// swizzle (chunk ^= (row>>1)&3) applied on the SOURCE address so the matching
// swizzled frag_ld reads are conflict-free.
__device__ __forceinline__ void stage_rows(ushort* lds, const ushort* src,
                                           size_t row0, int k0, int ld,
                                           int tid, int nslots) {
    int base = 0;
    for (; base + 256 <= nslots; base += 256) {
        const int slot = base + tid;
        const int r = slot >> 2, q = (slot & 3) ^ ((r >> 1) & 3);
        gload16(lds + (size_t)(base + (tid & 192)) * 8,
                src + (row0 + r) * (size_t)ld + k0 + q * 8);
    }
    const int rem = nslots - base;
    if (rem && tid < rem) {
        const int slot = base + tid;
        const int r = slot >> 2, q = (slot & 3) ^ ((r >> 1) & 3);
        gload16(lds + (size_t)base * 8,
                src + (row0 + r) * (size_t)ld + k0 + q * 8);
    }
}

// read one 16x32 fragment (lane l: row = fr*16 + (l&15), k-chunk = l>>4)
__device__ __forceinline__ u16x8 frag_ld(const ushort* tile, int fr, int lane) {
    const int rl = lane & 15;
    const int q  = (lane >> 4) ^ ((rl >> 1) & 3);
    return *(const u16x8*)(tile + ((fr * 16 + rl) * 32 + q * 8));
}

// ---- mini GEMM, fp16 inputs via global_load_lds: out[r][c] = sum_k A[r,k]B[c,k] ----
__device__ __forceinline__ void mini16(
        const ushort* __restrict__ A, int lda, const ushort* __restrict__ B, int ldb,
        int r0, int c0, int K, const float* __restrict__ bias,
        _Float16* __restrict__ outh, float* __restrict__ outf, int ldo,
        ushort* sA, ushort* sB, int tid) {
    const int lane = tid & 63, wid = tid >> 6;
    f32x4 acc[2][2];
    #pragma unroll
    for (int i = 0; i < 2; ++i)
        #pragma unroll
        for (int j = 0; j < 2; ++j) acc[i][j] = (f32x4)0.f;
    const int fa = (wid >> 1) * 2, fb = (wid & 1) * 2;
    for (int k0 = 0; k0 < K; k0 += 32) {
        stage_rows(sA, A, r0, k0, lda, tid, 256);
        stage_rows(sB, B, c0, k0, ldb, tid, 256);
        __syncthreads();
        f16x8 a0 = as_h(frag_ld(sA, fa, lane)), a1 = as_h(frag_ld(sA, fa + 1, lane));
        f16x8 b0 = as_h(frag_ld(sB, fb, lane)), b1 = as_h(frag_ld(sB, fb + 1, lane));
        acc[0][0] = __builtin_amdgcn_mfma_f32_16x16x32_f16(a0, b0, acc[0][0], 0, 0, 0);
        acc[0][1] = __builtin_amdgcn_mfma_f32_16x16x32_f16(a0, b1, acc[0][1], 0, 0, 0);
        acc[1][0] = __builtin_amdgcn_mfma_f32_16x16x32_f16(a1, b0, acc[1][0], 0, 0, 0);
        acc[1][1] = __builtin_amdgcn_mfma_f32_16x16x32_f16(a1, b1, acc[1][1], 0, 0, 0);
        __syncthreads();
    }
    #pragma unroll
    for (int i = 0; i < 2; ++i)
        #pragma unroll
        for (int j = 0; j < 2; ++j)
            #pragma unroll
            for (int rr = 0; rr < 4; ++rr) {
                const size_t row = r0 + (wid >> 1) * 32 + i * 16 + (lane >> 4) * 4 + rr;
                const int col = c0 + (wid & 1) * 32 + j * 16 + (lane & 15);
                const float v = acc[i][j][rr] + (bias ? bias[col] : 0.f);
                if (outh) outh[row * ldo + col] = (_Float16)v;
                else      outf[row * ldo + col] = v;
            }
}

// ---- mini GEMM, f32 inputs with inline fp16 convert (reg-staged, row guards) ----
__device__ __forceinline__ void mini_f32in(
        const float* __restrict__ A, int lda, int RA,
        const float* __restrict__ B, int ldb, int RB,
        int r0, int c0, int K, _Float16* __restrict__ out, int ldo,
        ushort* sA, ushort* sB, int tid) {
    const int lane = tid & 63, wid = tid >> 6;
    f32x4 acc[2][2];
    #pragma unroll
    for (int i = 0; i < 2; ++i)
        #pragma unroll
        for (int j = 0; j < 2; ++j) acc[i][j] = (f32x4)0.f;
    const int fa = (wid >> 1) * 2, fb = (wid & 1) * 2;
    for (int k0 = 0; k0 < K; k0 += 32) {
        #pragma unroll
        for (int p = 0; p < 2; ++p) {
            const int e = tid + p * 256;          // 512 8B-slots over [64][32]
            const int r = e >> 3, k4 = (e & 7) * 4;
            const int ad = r * 32 + (((k4 >> 3) ^ ((r >> 1) & 3)) << 3) + (k4 & 7);
            float4 va = (r0 + r < RA) ? *(const float4*)&A[(size_t)(r0 + r) * lda + k0 + k4]
                                      : make_float4(0.f, 0.f, 0.f, 0.f);
            f16x4 ha;
            ha[0] = (_Float16)va.x; ha[1] = (_Float16)va.y;
            ha[2] = (_Float16)va.z; ha[3] = (_Float16)va.w;
            *(f16x4*)&sA[ad] = ha;
            float4 vb = (c0 + r < RB) ? *(const float4*)&B[(size_t)(c0 + r) * ldb + k0 + k4]
                                      : make_float4(0.f, 0.f, 0.f, 0.f);
            f16x4 hb;
            hb[0] = (_Float16)vb.x; hb[1] = (_Float16)vb.y;
            hb[2] = (_Float16)vb.z; hb[3] = (_Float16)vb.w;
            *(f16x4*)&sB[ad] = hb;
        }
        __syncthreads();
        f16x8 a0 = as_h(frag_ld(sA, fa, lane)), a1 = as_h(frag_ld(sA, fa + 1, lane));
        f16x8 b0 = as_h(frag_ld(sB, fb, lane)), b1 = as_h(frag_ld(sB, fb + 1, lane));
        acc[0][0] = __builtin_amdgcn_mfma_f32_16x16x32_f16(a0, b0, acc[0][0], 0, 0, 0);
        acc[0][1] = __builtin_amdgcn_mfma_f32_16x16x32_f16(a0, b1, acc[0][1], 0, 0, 0);
        acc[1][0] = __builtin_amdgcn_mfma_f32_16x16x32_f16(a1, b0, acc[1][0], 0, 0, 0);
        acc[1][1] = __builtin_amdgcn_mfma_f32_16x16x32_f16(a1, b1, acc[1][1], 0, 0, 0);
        __syncthreads();
    }
    #pragma unroll
    for (int i = 0; i < 2; ++i)
        #pragma unroll
        for (int j = 0; j < 2; ++j)
            #pragma unroll
            for (int rr = 0; rr < 4; ++rr) {
                const size_t row = r0 + (wid >> 1) * 32 + i * 16 + (lane >> 4) * 4 + rr;
                const int col = c0 + (wid & 1) * 32 + j * 16 + (lane & 15);
                out[row * ldo + col] = (_Float16)acc[i][j][rr];
            }
}

// ================= STAGE A: everything reading only raw inputs =================
// grid: bvo(8) | bqk(512) | Hc(160) | WV(80) | cvtV(640) | cvtWv(2048) | cvtW2v(100) | prep(4096)
__global__ __launch_bounds__(256) void k_stageA(
        const float* __restrict__ feat, const float* __restrict__ w2v,
        const float* __restrict__ Wq,  const float* __restrict__ bq,
        const float* __restrict__ Wk,  const float* __restrict__ Wv,
        const float* __restrict__ bv,  const float* __restrict__ Wo,
        const float* __restrict__ bo,  const float* __restrict__ Vf,
        _Float16* __restrict__ f16, _Float16* __restrict__ poolx,
        _Float16* __restrict__ hc, _Float16* __restrict__ wvm,
        _Float16* __restrict__ v16, _Float16* __restrict__ wv16,
        _Float16* __restrict__ w2v16, float* __restrict__ bqk) {
    __shared__ __align__(16) char smem[51456];
    const int tid = threadIdx.x;
    int i = blockIdx.x;
    if (i < 8) {
        // bvo: poolx row 128 = bo[c] + sum_m bv[m] Wo[m,c]
        const int c = i * 256 + tid;
        float acc = bo[c];
        #pragma unroll 8
        for (int m = 0; m < Mn; ++m) acc = fmaf(bv[m], Wo[(size_t)m * Cn + c], acc);
        poolx[(size_t)128 * Cn + c] = (_Float16)acc;
    } else if ((i -= 8) < 512) {
        // bqk[c] = sum_m bq[m] Wk[c,m]  (wave per c)
        const int lane = tid & 63;
        const int c = i * 4 + (tid >> 6);
        float acc = 0.f;
        for (int m = lane; m < Mn; m += 64) acc = fmaf(bq[m], Wk[(size_t)c * Mn + m], acc);
        #pragma unroll
        for (int mm = 32; mm; mm >>= 1) acc += __shfl_xor(acc, mm);
        if (lane == 0) bqk[c] = acc;
    } else if ((i -= 512) < 160) {
        // Hc[c][l] = sum_m Wk[c,m] Wq[l,m]   [Cn][Lp]
        ushort* sA = (ushort*)smem;
        mini_f32in(Wk, Mn, 1 << 30, Wq, Mn, Ln,
                   (i / 5) * 64, (i % 5) * 64, Mn, hc, Lp, sA, sA + 2048, tid);
    } else if ((i -= 160) < 80) {
        // WV[s][m] = sum_c V[s,c] Wo[m,c]   [Sp][Mn]
        ushort* sA = (ushort*)smem;
        mini_f32in(Vf, Cn, Sn, Wo, Cn, 1 << 30,
                   (i / 16) * 64, (i % 16) * 64, Cn, wvm, Mn, sA, sA + 2048, tid);
    } else if ((i -= 80) < 640) {
        // cvt Vf -> v16 [Sp][Cn], pad rows 0
        const size_t idx = ((size_t)i * 256 + tid) * 4;
        const int r = (int)(idx >> 11);
        float4 v = (r < Sn) ? *(const float4*)&Vf[idx] : make_float4(0.f, 0.f, 0.f, 0.f);
        f16x4 h;
        h[0] = (_Float16)v.x; h[1] = (_Float16)v.y; h[2] = (_Float16)v.z; h[3] = (_Float16)v.w;
        *(f16x4*)&v16[idx] = h;
    } else if ((i -= 640) < 2048) {
        // cvt Wv -> wv16 [Cn][Mn]  (2048 blocks x 1024 elem = Cn*Mn; was 512 = R5/R6 BUG)
        const size_t idx = ((size_t)i * 256 + tid) * 4;
        const float4 v = *(const float4*)&Wv[idx];
        f16x4 h;
        h[0] = (_Float16)v.x; h[1] = (_Float16)v.y; h[2] = (_Float16)v.z; h[3] = (_Float16)v.w;
        *(f16x4*)&wv16[idx] = h;
    } else if ((i -= 2048) < 100) {
        // cvt w2v [Sn][Ln] -> w2v16 [Sp][Lp], zero-padded
        const int e0 = (i * 256 + tid) * 4;
        #pragma unroll
        for (int k = 0; k < 4; ++k) {
            const int e = e0 + k;
            const int r = e / Lp, cl = e - r * Lp;
            w2v16[e] = (r < Sn && cl < Ln) ? (_Float16)w2v[(size_t)r * Ln + cl] : (_Float16)0.f;
        }
    } else {
        // prep_feat: feat[b][c][n] -> f16[(b*196+n)][c] + poolx rows 0-127
        i -= 100;
        float (*t)[197] = (float(*)[197])smem;
        float (*pp)[4]  = (float(*)[4])(smem + 64 * 197 * 4);
        const int b = i >> 5, c0 = (i & 31) * 64;
        for (int idx = tid; idx < 64 * 49; idx += 256) {
            const int r = idx / 49, nq = idx - r * 49;
            const float4 v = *(const float4*)&feat[((size_t)b * Cn + c0 + r) * Nn + nq * 4];
            t[r][nq * 4 + 0] = v.x; t[r][nq * 4 + 1] = v.y;
            t[r][nq * 4 + 2] = v.z; t[r][nq * 4 + 3] = v.w;
        }
        __syncthreads();
        {
            const int c = tid >> 2, q = tid & 3;
            float s = 0.f;
            #pragma unroll
            for (int n = 0; n < 49; ++n) s += t[c][q * 49 + n];
            pp[c][q] = s;
        }
        for (int idx = tid; idx < Nn * 32; idx += 256) {
            const int n = idx >> 5, cp = (idx & 31) * 2;
            f16x4 h;
            h[0] = (_Float16)t[cp][n]; h[1] = (_Float16)t[cp + 1][n];
            *(uint*)&f16[((size_t)b * Nn + n) * Cn + c0 + cp] = *(uint*)&h;
        }
        __syncthreads();
        if (tid < 64)
            poolx[(size_t)b * Cn + c0 + tid] =
                (_Float16)((pp[tid][0] + pp[tid][1] + pp[tid][2] + pp[tid][3]) * (1.0f / Nn));
    }
}

// ================= STAGE B: qk | WWt | pv+cst =================
__global__ __launch_bounds__(256) void k_stageB(
        const ushort* __restrict__ w2v16, const ushort* __restrict__ hc,
        const float* __restrict__ bqk, const ushort* __restrict__ wvm,
        const ushort* __restrict__ wv16, const ushort* __restrict__ poolx,
        const ushort* __restrict__ v16,
        _Float16* __restrict__ qk16, _Float16* __restrict__ wwt16,
        float* __restrict__ pvf) {
    __shared__ __align__(16) ushort sA[2048], sB[2048];
    const int tid = threadIdx.x;
    int i = blockIdx.x;
    if (i < 160) {
        // qk[s][c] = sum_l w2v[s,l] Hc[c,l] + bqk[c]
        mini16(w2v16, Lp, hc, Lp, (i / 32) * 64, (i % 32) * 64, Lp,
               bqk, qk16, nullptr, Cn, sA, sB, tid);
    } else if ((i -= 160) < 160) {
        // WWt[s][c] = sum_m WV[s,m] Wv[c,m]
        mini16(wvm, Mn, wv16, Mn, (i / 32) * 64, (i % 32) * 64, Mn,
               nullptr, wwt16, nullptr, Cn, sA, sB, tid);
    } else {
        // pvf[row][s] = sum_c poolx[row,c] V[s,c]  (row 128 = cst)
        i -= 160;
        mini16(poolx, Cn, v16, Cn, (i / 5) * 64, (i % 5) * 64, Cn,
               nullptr, nullptr, pvf, Sp, sA, sB, tid);
    }
}

// ====== fused attention: double-buffered, __syncthreads-safe prefetch ======
// Per iteration: [sync: drains tile-t loads] -> issue tile-t+1 loads into the
// other buffer -> MFMA tile t (load latency hides under compute). Every
// cross-wave transition is protected by a full __syncthreads drain.
__global__ __launch_bounds__(256) void k_attn(
        const _Float16* __restrict__ f16, const _Float16* __restrict__ qk16,
        const _Float16* __restrict__ ww16, const float* __restrict__ pvf,
        float* __restrict__ out) {
    __shared__ __align__(16) ushort smem[2][10752];   // per buf: F 6656 | Q 2048 | W 2048
    const int tid = threadIdx.x, lane = tid & 63, wid = tid >> 6;
    const int id = blockIdx.x;
    const int xcd = id & 7, slot = id >> 3;
    const int b  = xcd * 16 + slot / 5;   // 5 sibling s-tiles -> same XCD
    const int s0 = (slot % 5) * 64;
    const size_t frow0 = (size_t)b * Nn;

    f32x4 sc[13], vw[13];
    #pragma unroll
    for (int j = 0; j < 13; ++j) { sc[j] = (f32x4)0.f; vw[j] = (f32x4)0.f; }

    auto stage3 = [&](int p, int k0) {
        ushort* s = smem[p];
        stage_rows(s,        (const ushort*)f16,  frow0, k0, Cn, tid, 832);
        stage_rows(s + 6656, (const ushort*)qk16, s0,    k0, Cn, tid, 256);
        stage_rows(s + 8704, (const ushort*)ww16, s0,    k0, Cn, tid, 256);
    };

    constexpr int NIT = Cn / 32;
    stage3(0, 0);
    for (int t = 0; t < NIT; ++t) {
        const int cur = t & 1;
        __syncthreads();                       // full drain: tile-t data ready
        if (t + 1 < NIT) stage3(cur ^ 1, (t + 1) * 32);   // prefetch under MFMA
        const ushort* sF = smem[cur];
        const f16x8 qf = as_h(frag_ld(sF + 6656, wid, lane));
        const f16x8 wf = as_h(frag_ld(sF + 8704, wid, lane));
        #pragma unroll
        for (int j = 0; j < 13; ++j) {
            const f16x8 ff = as_h(frag_ld(sF, j, lane));
            sc[j] = __builtin_amdgcn_mfma_f32_16x16x32_f16(qf, ff, sc[j], 0, 0, 0);
            vw[j] = __builtin_amdgcn_mfma_f32_16x16x32_f16(wf, ff, vw[j], 0, 0, 0);
        }
    }

    // per-row softmax over n (cols on 16-lane groups) + contraction
    const int g = lane & 15;
    #pragma unroll
    for (int rr = 0; rr < 4; ++rr) {
        float mx = -1e30f;
        #pragma unroll
        for (int j = 0; j < 13; ++j)
            if (j < 12 || g < 4) mx = fmaxf(mx, sc[j][rr]);
        #pragma unroll
        for (int mm = 1; mm < 16; mm <<= 1) mx = fmaxf(mx, __shfl_xor(mx, mm));
        float den = 0.f, num = 0.f;
        #pragma unroll
        for (int j = 0; j < 13; ++j)
            if (j < 12 || g < 4) {
                const float e = __expf(sc[j][rr] - mx);
                den += e;
                num = fmaf(e, vw[j][rr], num);
            }
        #pragma unroll
        for (int mm = 1; mm < 16; mm <<= 1) {
            den += __shfl_xor(den, mm);
            num += __shfl_xor(num, mm);
        }
        if (g == 0) {
            const int s = s0 + wid * 16 + (lane >> 4) * 4 + rr;
            if (s < Sn)
                out[(size_t)b * Sn + s] =
                    pvf[(size_t)b * Sp + s] + pvf[(size_t)128 * Sp + s] + num / den;
        }
    }
}

extern "C" void kernel_launch(void* const* d_in, const int* in_sizes, int n_in,
                              void* d_out, int out_size, void* d_ws, size_t ws_size,
                              hipStream_t stream) {
    (void)in_sizes; (void)n_in; (void)ws_size; (void)out_size;
    const float* feat = (const float*)d_in[0];
    const float* w2v  = (const float*)d_in[1];
    const float* Wq   = (const float*)d_in[2];
    const float* bq   = (const float*)d_in[3];
    const float* Wk   = (const float*)d_in[4];
    const float* Wv   = (const float*)d_in[6];
    const float* bv   = (const float*)d_in[7];
    const float* Wo   = (const float*)d_in[8];
    const float* bo   = (const float*)d_in[9];
    const float* Vf   = (const float*)d_in[10];
    float* out = (float*)d_out;
    float* ws  = (float*)d_ws;

    _Float16* f16   = (_Float16*)(ws + OFF_F16);
    _Float16* poolx = (_Float16*)(ws + OFF_POOLX);
    _Float16* hc    = (_Float16*)(ws + OFF_HC);
    _Float16* wvm   = (_Float16*)(ws + OFF_WVM);
    _Float16* v16   = (_Float16*)(ws + OFF_V16);
    _Float16* wv16  = (_Float16*)(ws + OFF_WV16);
    _Float16* w2v16 = (_Float16*)(ws + OFF_W2V);
    float*    bqk   = ws + OFF_BQK;
    _Float16* qk16  = (_Float16*)(ws + OFF_QK);
    _Float16* wwt16 = (_Float16*)(ws + OFF_WWT);
    float*    pvf   = ws + OFF_PVF;

    k_stageA<<<dim3(8 + 512 + 160 + 80 + 640 + 2048 + 100 + 4096), 256, 0, stream>>>(
        feat, w2v, Wq, bq, Wk, Wv, bv, Wo, bo, Vf,
        f16, poolx, hc, wvm, v16, wv16, w2v16, bqk);
    k_stageB<<<dim3(160 + 160 + 15), 256, 0, stream>>>(
        (const ushort*)w2v16, (const ushort*)hc, bqk, (const ushort*)wvm,
        (const ushort*)wv16, (const ushort*)poolx, (const ushort*)v16,
        qk16, wwt16, pvf);
    k_attn<<<dim3(640), 256, 0, stream>>>(f16, qk16, wwt16, pvf, out);
}